// Round 14
// baseline (323.507 us; speedup 1.0000x reference)
//
#include <hip/hip_runtime.h>
#include <math.h>

typedef __attribute__((ext_vector_type(8))) short bfrag;   // 8 x bf16 bits
typedef __attribute__((ext_vector_type(8))) unsigned short u16x8;
typedef __attribute__((ext_vector_type(4))) float f32x4;   // MFMA accumulator

// ---------- bf16 helpers ----------
__device__ __forceinline__ unsigned short bf16_rne(float f) {
  unsigned int u = __float_as_uint(f);
  u += 0x7FFFu + ((u >> 16) & 1u);
  return (unsigned short)(u >> 16);
}
__device__ __forceinline__ float bf16f(unsigned short h) {
  return __uint_as_float(((unsigned int)h) << 16);
}
__device__ __forceinline__ void split3(float x, unsigned short &o1, unsigned short &o2, unsigned short &o3) {
  o1 = bf16_rne(x);
  const float r1 = x - bf16f(o1);
  o2 = bf16_rne(r1);
  const float r2 = r1 - bf16f(o2);
  o3 = bf16_rne(r2);
}
__device__ __forceinline__ void split2(float x, unsigned short &o1, unsigned short &o2) {
  o1 = bf16_rne(x);
  o2 = bf16_rne(x - bf16f(o1));
}

// ---------- LayerNorm (row = 1024 f32) ----------
__global__ __launch_bounds__(256) void ln_kernel(const float* __restrict__ x,
                                                 const float* __restrict__ w,
                                                 float* __restrict__ out) {
  const int t = blockIdx.x;
  const int tid = threadIdx.x;
  const float4 v = *reinterpret_cast<const float4*>(&x[(size_t)t * 1024 + tid * 4]);
  float s = v.x + v.y + v.z + v.w;
  float ss = v.x * v.x + v.y * v.y + v.z * v.z + v.w * v.w;
#pragma unroll
  for (int off = 32; off; off >>= 1) {
    s += __shfl_xor(s, off);
    ss += __shfl_xor(ss, off);
  }
  __shared__ float red1[4], red2[4];
  if ((tid & 63) == 0) { red1[tid >> 6] = s; red2[tid >> 6] = ss; }
  __syncthreads();
  s = red1[0] + red1[1] + red1[2] + red1[3];
  ss = red2[0] + red2[1] + red2[2] + red2[3];
  const float mu = s * (1.0f / 1024.0f);
  const float var = ss * (1.0f / 1024.0f) - mu * mu;
  const float rstd = 1.0f / sqrtf(var + 1e-5f);
  const float4 wv = *reinterpret_cast<const float4*>(&w[tid * 4]);
  float4 o;
  o.x = (v.x - mu) * rstd * wv.x;
  o.y = (v.y - mu) * rstd * wv.y;
  o.z = (v.z - mu) * rstd * wv.z;
  o.w = (v.w - mu) * rstd * wv.w;
  *reinterpret_cast<float4*>(&out[(size_t)t * 1024 + tid * 4]) = o;
}

// ---------- fused LayerNorm -> split-3 bf16 planes ----------
__global__ __launch_bounds__(256) void ln_split3_kernel(
    const float* __restrict__ x, const float* __restrict__ w,
    unsigned short* __restrict__ d1, unsigned short* __restrict__ d2,
    unsigned short* __restrict__ d3) {
  const int t = blockIdx.x;
  const int tid = threadIdx.x;
  const float4 v = *reinterpret_cast<const float4*>(&x[(size_t)t * 1024 + tid * 4]);
  float s = v.x + v.y + v.z + v.w;
  float ss = v.x * v.x + v.y * v.y + v.z * v.z + v.w * v.w;
#pragma unroll
  for (int off = 32; off; off >>= 1) {
    s += __shfl_xor(s, off);
    ss += __shfl_xor(ss, off);
  }
  __shared__ float red1[4], red2[4];
  if ((tid & 63) == 0) { red1[tid >> 6] = s; red2[tid >> 6] = ss; }
  __syncthreads();
  s = red1[0] + red1[1] + red1[2] + red1[3];
  ss = red2[0] + red2[1] + red2[2] + red2[3];
  const float mu = s * (1.0f / 1024.0f);
  const float var = ss * (1.0f / 1024.0f) - mu * mu;
  const float rstd = 1.0f / sqrtf(var + 1e-5f);
  const float4 wv = *reinterpret_cast<const float4*>(&w[tid * 4]);
  float4 o;
  o.x = (v.x - mu) * rstd * wv.x;
  o.y = (v.y - mu) * rstd * wv.y;
  o.z = (v.z - mu) * rstd * wv.z;
  o.w = (v.w - mu) * rstd * wv.w;
  ushort4 a, b, c;
  split3(o.x, a.x, b.x, c.x);
  split3(o.y, a.y, b.y, c.y);
  split3(o.z, a.z, b.z, c.z);
  split3(o.w, a.w, b.w, c.w);
  const int i = t * 256 + tid;
  reinterpret_cast<ushort4*>(d1)[i] = a;
  reinterpret_cast<ushort4*>(d2)[i] = b;
  reinterpret_cast<ushort4*>(d3)[i] = c;
}

// ---------- fused split-3 transposes of Wq/Wk/Wv/Wo: [K][N] f32 -> 3x [N][K] bf16 ----------
__global__ __launch_bounds__(256) void split3t_all_kernel(
    const float* __restrict__ Wq, const float* __restrict__ Wk,
    const float* __restrict__ Wv, const float* __restrict__ Wo,
    unsigned short* __restrict__ q1, unsigned short* __restrict__ q2, unsigned short* __restrict__ q3,
    unsigned short* __restrict__ k1, unsigned short* __restrict__ k2, unsigned short* __restrict__ k3,
    unsigned short* __restrict__ v1, unsigned short* __restrict__ v2, unsigned short* __restrict__ v3,
    unsigned short* __restrict__ o1, unsigned short* __restrict__ o2, unsigned short* __restrict__ o3) {
  __shared__ float tile[32][33];
  const int bid = blockIdx.x;
  const float* src;
  unsigned short *d1, *d2, *d3;
  int N, local;
  if (bid < 1024)      { src = Wq; d1 = q1; d2 = q2; d3 = q3; N = 1024; local = bid; }
  else if (bid < 1280) { src = Wk; d1 = k1; d2 = k2; d3 = k3; N = 256;  local = bid - 1024; }
  else if (bid < 1536) { src = Wv; d1 = v1; d2 = v2; d3 = v3; N = 256;  local = bid - 1280; }
  else                 { src = Wo; d1 = o1; d2 = o2; d3 = o3; N = 1024; local = bid - 1536; }
  const int K = 1024;
  const int k0 = (local & 31) * 32, n0 = (local >> 5) * 32;
  const int tx = threadIdx.x & 31, ty = threadIdx.x >> 5;
#pragma unroll
  for (int i = 0; i < 4; ++i)
    tile[ty + i * 8][tx] = src[(size_t)(k0 + ty + i * 8) * N + n0 + tx];
  __syncthreads();
#pragma unroll
  for (int i = 0; i < 4; ++i) {
    const float v = tile[tx][ty + i * 8];
    unsigned short s1, s2, s3;
    split3(v, s1, s2, s3);
    const size_t o = (size_t)(n0 + ty + i * 8) * K + k0 + tx;
    d1[o] = s1; d2[o] = s2; d3[o] = s3;
  }
}

// ---------- shared pre-split GEMM body, 64x64 tile, 4 waves, 2x2 acc ----------
__device__ __forceinline__ void gemm64_body(
    const unsigned short* __restrict__ A1, const unsigned short* __restrict__ A2,
    const unsigned short* __restrict__ A3, const unsigned short* __restrict__ B1,
    const unsigned short* __restrict__ B2, const unsigned short* __restrict__ B3,
    float* __restrict__ C, const float* __restrict__ Res,
    int N, int K, int doclip, int m0, int n0) {
  __shared__ alignas(16) unsigned short As[3][64][40];
  __shared__ alignas(16) unsigned short Bs[3][64][40];
  const int tid = threadIdx.x;
  const int w = tid >> 6, l = tid & 63;
  const int wm = (w >> 1) * 32, wn = (w & 1) * 32;
  const int lr = l & 15, lg = l >> 4;
  const int arow = tid >> 2, kslot = tid & 3;   // row 0..63, 8-k slot 0..3

  const unsigned short* Ap[3] = {A1, A2, A3};
  const unsigned short* Bp[3] = {B1, B2, B3};

  f32x4 acc[2][2] = {{{0.f,0.f,0.f,0.f},{0.f,0.f,0.f,0.f}},
                     {{0.f,0.f,0.f,0.f},{0.f,0.f,0.f,0.f}}};

  for (int k0 = 0; k0 < K; k0 += 32) {
#pragma unroll
    for (int s = 0; s < 3; ++s) {
      *reinterpret_cast<u16x8*>(&As[s][arow][kslot * 8]) =
          *reinterpret_cast<const u16x8*>(&Ap[s][(size_t)(m0 + arow) * K + k0 + kslot * 8]);
      *reinterpret_cast<u16x8*>(&Bs[s][arow][kslot * 8]) =
          *reinterpret_cast<const u16x8*>(&Bp[s][(size_t)(n0 + arow) * K + k0 + kslot * 8]);
    }
    __syncthreads();
    bfrag af[2][3], bg[2][3];
#pragma unroll
    for (int mi = 0; mi < 2; ++mi)
#pragma unroll
      for (int s = 0; s < 3; ++s)
        af[mi][s] = *reinterpret_cast<const bfrag*>(&As[s][wm + mi * 16 + lr][lg * 8]);
#pragma unroll
    for (int ni = 0; ni < 2; ++ni)
#pragma unroll
      for (int s = 0; s < 3; ++s)
        bg[ni][s] = *reinterpret_cast<const bfrag*>(&Bs[s][wn + ni * 16 + lr][lg * 8]);
#pragma unroll
    for (int mi = 0; mi < 2; ++mi)
#pragma unroll
      for (int ni = 0; ni < 2; ++ni) {
        f32x4 c = acc[mi][ni];
        c = __builtin_amdgcn_mfma_f32_16x16x32_bf16(af[mi][2], bg[ni][0], c, 0, 0, 0);
        c = __builtin_amdgcn_mfma_f32_16x16x32_bf16(af[mi][1], bg[ni][1], c, 0, 0, 0);
        c = __builtin_amdgcn_mfma_f32_16x16x32_bf16(af[mi][0], bg[ni][2], c, 0, 0, 0);
        c = __builtin_amdgcn_mfma_f32_16x16x32_bf16(af[mi][1], bg[ni][0], c, 0, 0, 0);
        c = __builtin_amdgcn_mfma_f32_16x16x32_bf16(af[mi][0], bg[ni][1], c, 0, 0, 0);
        c = __builtin_amdgcn_mfma_f32_16x16x32_bf16(af[mi][0], bg[ni][0], c, 0, 0, 0);
        acc[mi][ni] = c;
      }
    __syncthreads();
  }
#pragma unroll
  for (int mi = 0; mi < 2; ++mi)
#pragma unroll
    for (int ni = 0; ni < 2; ++ni)
#pragma unroll
      for (int r = 0; r < 4; ++r) {
        const int row = m0 + wm + mi * 16 + lg * 4 + r;
        const int col = n0 + wn + ni * 16 + lr;
        float vv = acc[mi][ni][r];
        if (doclip) vv = fminf(fmaxf(vv, -8.0f), 8.0f);
        if (Res) vv += Res[(size_t)row * N + col];
        C[(size_t)row * N + col] = vv;
      }
}

// generic pre-split GEMM (used for Wo): grid (M/64, N/64)
__global__ __launch_bounds__(256) void gemm_ps_kernel(
    const unsigned short* __restrict__ A1, const unsigned short* __restrict__ A2,
    const unsigned short* __restrict__ A3, const unsigned short* __restrict__ B1,
    const unsigned short* __restrict__ B2, const unsigned short* __restrict__ B3,
    float* __restrict__ C, const float* __restrict__ Res,
    int N, int K, int doclip) {
  gemm64_body(A1, A2, A3, B1, B2, B3, C, Res, N, K, doclip,
              blockIdx.x * 64, blockIdx.y * 64);
}

// fused Q/K/V GEMM: blockIdx.y 0..15 -> Wq, 16..19 -> Wk, 20..23 -> Wv
__global__ __launch_bounds__(256) void gemm_qkv_kernel(
    const unsigned short* __restrict__ A1, const unsigned short* __restrict__ A2,
    const unsigned short* __restrict__ A3,
    const unsigned short* __restrict__ Q1, const unsigned short* __restrict__ Q2,
    const unsigned short* __restrict__ Q3,
    const unsigned short* __restrict__ K1, const unsigned short* __restrict__ K2,
    const unsigned short* __restrict__ K3,
    const unsigned short* __restrict__ V1, const unsigned short* __restrict__ V2,
    const unsigned short* __restrict__ V3,
    float* __restrict__ qb, float* __restrict__ kb, float* __restrict__ vb) {
  const int by = blockIdx.y;
  const unsigned short *B1, *B2, *B3;
  float* C;
  int N, n0;
  if (by < 16)      { B1 = Q1; B2 = Q2; B3 = Q3; C = qb; N = 1024; n0 = by * 64; }
  else if (by < 20) { B1 = K1; B2 = K2; B3 = K3; C = kb; N = 256;  n0 = (by - 16) * 64; }
  else              { B1 = V1; B2 = V2; B3 = V3; C = vb; N = 256;  n0 = (by - 20) * 64; }
  gemm64_body(A1, A2, A3, B1, B2, B3, C, nullptr, N, 1024, 1, blockIdx.x * 64, n0);
}

// ---------- RoPE table (f64 trig, computed once) ----------
__global__ void rope_table_kernel(const int* __restrict__ posids,
                                  float* __restrict__ cosT, float* __restrict__ sinT) {
  const int t = blockIdx.x * 8 + (threadIdx.x >> 5);
  const int i = threadIdx.x & 31;
  const double ang = (double)posids[t] * pow(500000.0, -(double)i / 32.0);
  cosT[t * 32 + i] = (float)cos(ang);
  sinT[t * 32 + i] = (float)sin(ang);
}

// ---------- prep: fused k-RoPE + split-2 bf16 K (row-major) and V (transposed) ----------
__global__ __launch_bounds__(256) void prep_kv_kernel(
    const float* __restrict__ k, const float* __restrict__ v,
    const float* __restrict__ cosT, const float* __restrict__ sinT,
    unsigned short* __restrict__ Kp1, unsigned short* __restrict__ Kp2,
    unsigned short* __restrict__ Vp1, unsigned short* __restrict__ Vp2) {
  const int key = blockIdx.x;          // 0..1023
  const int kvh = threadIdx.x >> 6;    // 0..3
  const int d = threadIdx.x & 63;
  const int dd = d & 31;
  const float* kbase = &k[((size_t)key * 4 + kvh) * 64];
  const float c = cosT[key * 32 + dd], s = sinT[key * 32 + dd];
  const float u1 = kbase[dd], u2 = kbase[dd + 32];
  const float kk = (d < 32) ? (u1 * c - u2 * s) : (u2 * c + u1 * s);
  const float vv = v[((size_t)key * 4 + kvh) * 64 + d];
  unsigned short a1, a2, b1, b2;
  split2(kk, a1, a2);
  split2(vv, b1, b2);
  const size_t ki = ((size_t)kvh * 1024 + key) * 64 + d;
  Kp1[ki] = a1; Kp2[ki] = a2;
  const size_t vi = ((size_t)kvh * 64 + d) * 1024 + key;
  Vp1[vi] = b1; Vp2[vi] = b2;
}

// ---------- causal GQA flash attention, split-2 bf16 MFMA ----------
// q-RoPE fused into the Q-fragment load; epilogue writes split-3 planes
__global__ __launch_bounds__(256) void attn_kernel(
    const float* __restrict__ q,
    const float* __restrict__ cosT, const float* __restrict__ sinT,
    const unsigned short* __restrict__ Kp1, const unsigned short* __restrict__ Kp2,
    const unsigned short* __restrict__ Vp1, const unsigned short* __restrict__ Vp2,
    unsigned short* __restrict__ o1, unsigned short* __restrict__ o2,
    unsigned short* __restrict__ o3) {
  const int qt = blockIdx.x, h = blockIdx.y, kvh = h >> 2;
  __shared__ unsigned short Ks1[64][72], Ks2[64][72], Vt1[64][72], Vt2[64][72];
  __shared__ unsigned short Ps1[4][16][72], Ps2[4][16][72];
  const int tid = threadIdx.x;
  const int w = tid >> 6, l = tid & 63;
  const int lr = l & 15, lg = l >> 4;

  bfrag aq1[2], aq2[2];
  {
    const int tq = qt * 64 + w * 16 + lr;
    const float* qrow = &q[((size_t)tq * 16 + h) * 64];
    const float4 f00 = *reinterpret_cast<const float4*>(qrow + lg * 8);
    const float4 f01 = *reinterpret_cast<const float4*>(qrow + lg * 8 + 4);
    const float4 f10 = *reinterpret_cast<const float4*>(qrow + 32 + lg * 8);
    const float4 f11 = *reinterpret_cast<const float4*>(qrow + 32 + lg * 8 + 4);
    const float x0[8] = {f00.x, f00.y, f00.z, f00.w, f01.x, f01.y, f01.z, f01.w};
    const float x1[8] = {f10.x, f10.y, f10.z, f10.w, f11.x, f11.y, f11.z, f11.w};
#pragma unroll
    for (int j = 0; j < 8; ++j) {
      const float c = cosT[tq * 32 + lg * 8 + j];
      const float s = sinT[tq * 32 + lg * 8 + j];
      const float r0 = x0[j] * c - x1[j] * s;
      const float r1 = x1[j] * c + x0[j] * s;
      unsigned short p1, p2;
      split2(r0 * 0.125f, p1, p2);
      aq1[0][j] = (short)p1; aq2[0][j] = (short)p2;
      split2(r1 * 0.125f, p1, p2);
      aq1[1][j] = (short)p1; aq2[1][j] = (short)p2;
    }
  }

  f32x4 accO[4] = {{0.f,0.f,0.f,0.f},{0.f,0.f,0.f,0.f},{0.f,0.f,0.f,0.f},{0.f,0.f,0.f,0.f}};
  float mrun[4] = {-INFINITY, -INFINITY, -INFINITY, -INFINITY};
  float lrun[4] = {0.f, 0.f, 0.f, 0.f};

  for (int ti = 0; ti <= qt; ++ti) {
    const int s0 = ti * 64;
    {
      const size_t kbase = ((size_t)kvh * 1024 + s0 + l) * 64 + w * 16;
      *reinterpret_cast<u16x8*>(&Ks1[l][w * 16])     = *reinterpret_cast<const u16x8*>(&Kp1[kbase]);
      *reinterpret_cast<u16x8*>(&Ks1[l][w * 16 + 8]) = *reinterpret_cast<const u16x8*>(&Kp1[kbase + 8]);
      *reinterpret_cast<u16x8*>(&Ks2[l][w * 16])     = *reinterpret_cast<const u16x8*>(&Kp2[kbase]);
      *reinterpret_cast<u16x8*>(&Ks2[l][w * 16 + 8]) = *reinterpret_cast<const u16x8*>(&Kp2[kbase + 8]);
      const size_t vbase = ((size_t)kvh * 64 + l) * 1024 + s0 + w * 16;
      *reinterpret_cast<u16x8*>(&Vt1[l][w * 16])     = *reinterpret_cast<const u16x8*>(&Vp1[vbase]);
      *reinterpret_cast<u16x8*>(&Vt1[l][w * 16 + 8]) = *reinterpret_cast<const u16x8*>(&Vp1[vbase + 8]);
      *reinterpret_cast<u16x8*>(&Vt2[l][w * 16])     = *reinterpret_cast<const u16x8*>(&Vp2[vbase]);
      *reinterpret_cast<u16x8*>(&Vt2[l][w * 16 + 8]) = *reinterpret_cast<const u16x8*>(&Vp2[vbase + 8]);
    }
    __syncthreads();

    f32x4 accS[4] = {{0.f,0.f,0.f,0.f},{0.f,0.f,0.f,0.f},{0.f,0.f,0.f,0.f},{0.f,0.f,0.f,0.f}};
#pragma unroll
    for (int ks = 0; ks < 2; ++ks) {
      const int koff = ks * 32 + lg * 8;
#pragma unroll
      for (int ni = 0; ni < 4; ++ni) {
        const bfrag b1 = *reinterpret_cast<const bfrag*>(&Ks1[ni * 16 + lr][koff]);
        const bfrag b2 = *reinterpret_cast<const bfrag*>(&Ks2[ni * 16 + lr][koff]);
        f32x4 c = accS[ni];
        c = __builtin_amdgcn_mfma_f32_16x16x32_bf16(aq1[ks], b2, c, 0, 0, 0);
        c = __builtin_amdgcn_mfma_f32_16x16x32_bf16(aq2[ks], b1, c, 0, 0, 0);
        c = __builtin_amdgcn_mfma_f32_16x16x32_bf16(aq1[ks], b1, c, 0, 0, 0);
        accS[ni] = c;
      }
    }
    if (ti == qt) {
      const int rowb = w * 16 + lg * 4;
#pragma unroll
      for (int ni = 0; ni < 4; ++ni)
#pragma unroll
        for (int r = 0; r < 4; ++r)
          if (ni * 16 + lr > rowb + r) accS[ni][r] = -INFINITY;
    }
    float alpha[4];
#pragma unroll
    for (int r = 0; r < 4; ++r) {
      float tm = fmaxf(fmaxf(accS[0][r], accS[1][r]), fmaxf(accS[2][r], accS[3][r]));
      tm = fmaxf(tm, __shfl_xor(tm, 1));
      tm = fmaxf(tm, __shfl_xor(tm, 2));
      tm = fmaxf(tm, __shfl_xor(tm, 4));
      tm = fmaxf(tm, __shfl_xor(tm, 8));
      const float mnew = fmaxf(mrun[r], tm);
      alpha[r] = __expf(mrun[r] - mnew);
      mrun[r] = mnew;
      float ps = 0.f;
#pragma unroll
      for (int ni = 0; ni < 4; ++ni) {
        const float pv = __expf(accS[ni][r] - mnew);
        accS[ni][r] = pv;
        ps += pv;
      }
      ps += __shfl_xor(ps, 1);
      ps += __shfl_xor(ps, 2);
      ps += __shfl_xor(ps, 4);
      ps += __shfl_xor(ps, 8);
      lrun[r] = lrun[r] * alpha[r] + ps;
    }
#pragma unroll
    for (int ni = 0; ni < 4; ++ni)
#pragma unroll
      for (int r = 0; r < 4; ++r) {
        const float pv = accS[ni][r];
        unsigned short p1, p2;
        split2(pv, p1, p2);
        Ps1[w][lg * 4 + r][ni * 16 + lr] = p1;
        Ps2[w][lg * 4 + r][ni * 16 + lr] = p2;
      }
#pragma unroll
    for (int ni = 0; ni < 4; ++ni)
#pragma unroll
      for (int r = 0; r < 4; ++r) accO[ni][r] *= alpha[r];

    asm volatile("s_waitcnt lgkmcnt(0)" ::: "memory");

#pragma unroll
    for (int kk = 0; kk < 2; ++kk) {
      const int koff = kk * 32 + lg * 8;
      const bfrag pa1 = *reinterpret_cast<const bfrag*>(&Ps1[w][lr][koff]);
      const bfrag pa2 = *reinterpret_cast<const bfrag*>(&Ps2[w][lr][koff]);
#pragma unroll
      for (int ni = 0; ni < 4; ++ni) {
        const bfrag vb1 = *reinterpret_cast<const bfrag*>(&Vt1[ni * 16 + lr][koff]);
        const bfrag vb2 = *reinterpret_cast<const bfrag*>(&Vt2[ni * 16 + lr][koff]);
        f32x4 c = accO[ni];
        c = __builtin_amdgcn_mfma_f32_16x16x32_bf16(pa1, vb2, c, 0, 0, 0);
        c = __builtin_amdgcn_mfma_f32_16x16x32_bf16(pa2, vb1, c, 0, 0, 0);
        c = __builtin_amdgcn_mfma_f32_16x16x32_bf16(pa1, vb1, c, 0, 0, 0);
        accO[ni] = c;
      }
    }
    __syncthreads();
  }

  const int tqo = qt * 64 + w * 16 + lg * 4;
#pragma unroll
  for (int r = 0; r < 4; ++r) {
    const float inv = 1.0f / lrun[r];
#pragma unroll
    for (int ni = 0; ni < 4; ++ni) {
      const size_t oi = (size_t)(tqo + r) * 1024 + h * 64 + ni * 16 + lr;
      unsigned short s1, s2, s3;
      split3(accO[ni][r] * inv, s1, s2, s3);
      o1[oi] = s1; o2[oi] = s2; o3[oi] = s3;
    }
  }
}

// ---------- router: top-2 of softmax(h2 @ Wr) ----------
__global__ __launch_bounds__(64) void router_kernel(const float* __restrict__ h2,
                                                    const float* __restrict__ Wr,
                                                    int* __restrict__ eidx,
                                                    float* __restrict__ egate) {
  const int t = blockIdx.x;
  const int l = threadIdx.x;
  float p[8];
#pragma unroll
  for (int e = 0; e < 8; ++e) p[e] = 0.f;
  for (int d = l; d < 1024; d += 64) {
    const float x = h2[(size_t)t * 1024 + d];
    const float4 w0 = *reinterpret_cast<const float4*>(&Wr[d * 8]);
    const float4 w1 = *reinterpret_cast<const float4*>(&Wr[d * 8 + 4]);
    p[0] += x * w0.x; p[1] += x * w0.y; p[2] += x * w0.z; p[3] += x * w0.w;
    p[4] += x * w1.x; p[5] += x * w1.y; p[6] += x * w1.z; p[7] += x * w1.w;
  }
#pragma unroll
  for (int off = 32; off; off >>= 1) {
#pragma unroll
    for (int e = 0; e < 8; ++e) p[e] += __shfl_xor(p[e], off);
  }
  if (l == 0) {
    int i0 = 0; float b0 = p[0];
#pragma unroll
    for (int e = 1; e < 8; ++e) if (p[e] > b0) { b0 = p[e]; i0 = e; }
    int i1 = -1; float b1 = -INFINITY;
#pragma unroll
    for (int e = 0; e < 8; ++e) if (e != i0 && p[e] > b1) { b1 = p[e]; i1 = e; }
    const float ex = expf(b1 - b0);
    eidx[t * 2] = i0; eidx[t * 2 + 1] = i1;
    egate[t * 2] = 1.0f / (1.0f + ex);
    egate[t * 2 + 1] = ex / (1.0f + ex);
  }
}

// ---------- dispatch: replicate jnp cumsum slot assignment ----------
__global__ __launch_bounds__(256) void dispatch_kernel(
    const int* __restrict__ eidx, int* __restrict__ cnt,
    int* __restrict__ slot_token, int* __restrict__ entry_slot) {
  __shared__ unsigned char ef[2048];
  __shared__ unsigned short ch[256][8];
  const int tid = threadIdx.x;
  for (int i = tid; i < 2048; i += 256) ef[i] = (unsigned char)eidx[i];
  __syncthreads();
  int loc[8];
#pragma unroll
  for (int e = 0; e < 8; ++e) loc[e] = 0;
  const int base = tid * 8;
  for (int j = 0; j < 8; ++j) {
    const int ee = ef[base + j];
#pragma unroll
    for (int e = 0; e < 8; ++e) loc[e] += (ee == e);
  }
#pragma unroll
  for (int e = 0; e < 8; ++e) ch[tid][e] = (unsigned short)loc[e];
  __syncthreads();
  int pre[8];
#pragma unroll
  for (int e = 0; e < 8; ++e) pre[e] = 0;
  for (int t2 = 0; t2 < tid; ++t2) {
#pragma unroll
    for (int e = 0; e < 8; ++e) pre[e] += ch[t2][e];
  }
  if (tid == 255) {
#pragma unroll
    for (int e = 0; e < 8; ++e) cnt[e] = min(pre[e] + loc[e], 512);
  }
  for (int j = 0; j < 8; ++j) {
    const int i = base + j;
    const int ee = ef[i];
    int slot = 0;
#pragma unroll
    for (int e = 0; e < 8; ++e) {
      if (e == ee) { slot = pre[e]; pre[e] = pre[e] + 1; }
    }
    if (slot < 512) {
      slot_token[ee * 512 + slot] = i >> 1;
      entry_slot[i] = slot;
    } else {
      entry_slot[i] = -1;
    }
  }
}

// ---------- pre-convert dispatched tokens to bf16: xbf[e][slot][1024] ----------
__global__ __launch_bounds__(256) void moe_xbf_kernel(
    const float* __restrict__ h2, const int* __restrict__ cnt,
    const int* __restrict__ slot_token, unsigned short* __restrict__ xbf) {
  const int row = blockIdx.x;          // e*512 + slot
  const int e = row >> 9, slot = row & 511;
  const int tid = threadIdx.x;
  ushort4 o;
  if (slot < cnt[e]) {
    const int tok = slot_token[row];
    const float4 f = *reinterpret_cast<const float4*>(&h2[(size_t)tok * 1024 + tid * 4]);
    o = make_ushort4(bf16_rne(f.x), bf16_rne(f.y), bf16_rne(f.z), bf16_rne(f.w));
  } else {
    o = make_ushort4(0, 0, 0, 0);
  }
  *reinterpret_cast<ushort4*>(&xbf[(size_t)row * 1024 + tid * 4]) = o;
}

// ---------- MoE pass 1 (BK=128, 8 steps): act = silu(X@Wg)*(X@Wu) ----------
// Round-5 skeleton with halved step count. grid 512: e = bx&7, nt = bx>>3 (BN=32).
__global__ __launch_bounds__(256, 2) void moe_mlp1_kernel(
    const unsigned short* __restrict__ xbf, const float* __restrict__ Wg,
    const float* __restrict__ Wu, const int* __restrict__ cnt,
    unsigned short* __restrict__ act) {
  const int bx = blockIdx.x;
  const int e = bx & 7, nt = bx >> 3;
  const int n0 = nt * 32;
  const int ce = cnt[e];
  if (ce <= 0) return;
  __shared__ alignas(16) unsigned short BgL[2][32][136], BuL[2][32][136];
  const int tid = threadIdx.x;
  const int w = tid >> 6, l = tid & 63;
  const int lr = l & 15, lg = l >> 4;
  const int wc = tid & 31, kq = tid >> 5;    // col 0..31, k-16-group 0..7
  const float* WgE = Wg + (size_t)e * 1024 * 2048 + (size_t)kq * 16 * 2048 + n0 + wc;
  const float* WuE = Wu + (size_t)e * 1024 * 2048 + (size_t)kq * 16 * 2048 + n0 + wc;
  const unsigned short* xbE = xbf + (size_t)e * 512 * 1024;

  f32x4 accG[8][2], accU[8][2];
#pragma unroll
  for (int mi = 0; mi < 8; ++mi)
#pragma unroll
    for (int ni = 0; ni < 2; ++ni) {
      accG[mi][ni] = (f32x4){0.f, 0.f, 0.f, 0.f};
      accU[mi][ni] = (f32x4){0.f, 0.f, 0.f, 0.f};
    }

  float wgr[16], wur[16];
  // prologue: W(0) load+convert+store, then issue W(1)
  {
    float tg[16], tu[16];
#pragma unroll
    for (int j = 0; j < 16; ++j) { tg[j] = WgE[(size_t)j * 2048]; tu[j] = WuE[(size_t)j * 2048]; }
    u16x8 ga, gb, ua, ub;
#pragma unroll
    for (int j = 0; j < 8; ++j) {
      ga[j] = bf16_rne(tg[j]);     gb[j] = bf16_rne(tg[j + 8]);
      ua[j] = bf16_rne(tu[j]);     ub[j] = bf16_rne(tu[j + 8]);
    }
    *reinterpret_cast<u16x8*>(&BgL[0][wc][kq * 16])     = ga;
    *reinterpret_cast<u16x8*>(&BgL[0][wc][kq * 16 + 8]) = gb;
    *reinterpret_cast<u16x8*>(&BuL[0][wc][kq * 16])     = ua;
    *reinterpret_cast<u16x8*>(&BuL[0][wc][kq * 16 + 8]) = ub;
  }
#pragma unroll
  for (int j = 0; j < 16; ++j) {
    wgr[j] = WgE[(size_t)(128 + j) * 2048];
    wur[j] = WuE[(size_t)(128 + j) * 2048];
  }
  __syncthreads();

  for (int t = 0; t < 8; ++t) {
    const int cur = t & 1;
    bfrag bgf[2][4], buf2[2][4];
#pragma unroll
    for (int ni = 0; ni < 2; ++ni)
#pragma unroll
      for (int kf = 0; kf < 4; ++kf) {
        bgf[ni][kf]  = *reinterpret_cast<const bfrag*>(&BgL[cur][ni * 16 + lr][kf * 32 + lg * 8]);
        buf2[ni][kf] = *reinterpret_cast<const bfrag*>(&BuL[cur][ni * 16 + lr][kf * 32 + lg * 8]);
      }
    u16x8 ga, gb, ua, ub;
    if (t < 7) {
#pragma unroll
      for (int j = 0; j < 8; ++j) {
        ga[j] = bf16_rne(wgr[j]);     gb[j] = bf16_rne(wgr[j + 8]);
        ua[j] = bf16_rne(wur[j]);     ub[j] = bf16_rne(wur[j + 8]);
      }
    }
    if (t < 6) {
      const size_t kb = (size_t)(t + 2) * 128;
#pragma unroll
      for (int j = 0; j < 16; ++j) {
        wgr[j] = WgE[(kb + j) * 2048];
        wur[j] = WuE[(kb + j) * 2048];
      }
    }
    const int kA = t * 128 + lg * 8;
#pragma unroll
    for (int mi = 0; mi < 8; ++mi) {
      const int row0 = (mi * 4 + w) * 16;   // wave-interleaved 16-row groups
      if (row0 < ce) {
        const unsigned short* ap = &xbE[(size_t)(row0 + lr) * 1024 + kA];
        const bfrag a0 = *reinterpret_cast<const bfrag*>(ap);
        const bfrag a1 = *reinterpret_cast<const bfrag*>(ap + 32);
        const bfrag a2 = *reinterpret_cast<const bfrag*>(ap + 64);
        const bfrag a3 = *reinterpret_cast<const bfrag*>(ap + 96);
#pragma unroll
        for (int ni = 0; ni < 2; ++ni) {
          accG[mi][ni] = __builtin_amdgcn_mfma_f32_16x16x32_bf16(a0, bgf[ni][0], accG[mi][ni], 0, 0, 0);
          accG[mi][ni] = __builtin_amdgcn_mfma_f32_16x16x32_bf16(a1, bgf[ni][1], accG[mi][ni], 0, 0, 0);
          accG[mi][ni] = __builtin_amdgcn_mfma_f32_16x16x32_bf16(a2, bgf[ni][2], accG[mi][ni], 0, 0, 0);
          accG[mi][ni] = __builtin_amdgcn_mfma_f32_16x16x32_bf16(a3, bgf[ni][3], accG[mi][ni], 0, 0, 0);
          accU[mi][ni] = __builtin_amdgcn_mfma_f32_16x16x32_bf16(a0, buf2[ni][0], accU[mi][ni], 0, 0, 0);
          accU[mi][ni] = __builtin_amdgcn_mfma_f32_16x16x32_bf16(a1, buf2[ni][1], accU[mi][ni], 0, 0, 0);
          accU[mi][ni] = __builtin_amdgcn_mfma_f32_16x16x32_bf16(a2, buf2[ni][2], accU[mi][ni], 0, 0, 0);
          accU[mi][ni] = __builtin_amdgcn_mfma_f32_16x16x32_bf16(a3, buf2[ni][3], accU[mi][ni], 0, 0, 0);
        }
      }
    }
    if (t < 7) {
      *reinterpret_cast<u16x8*>(&BgL[cur ^ 1][wc][kq * 16])     = ga;
      *reinterpret_cast<u16x8*>(&BgL[cur ^ 1][wc][kq * 16 + 8]) = gb;
      *reinterpret_cast<u16x8*>(&BuL[cur ^ 1][wc][kq * 16])     = ua;
      *reinterpret_cast<u16x8*>(&BuL[cur ^ 1][wc][kq * 16 + 8]) = ub;
    }
    __syncthreads();
  }
  // epilogue
#pragma unroll
  for (int mi = 0; mi < 8; ++mi) {
    const int row0 = (mi * 4 + w) * 16;
    if (row0 < ce) {
#pragma unroll
      for (int r = 0; r < 4; ++r) {
        const int m = row0 + lg * 4 + r;
        if (m < ce) {
#pragma unroll
          for (int ni = 0; ni < 2; ++ni) {
            const float gg = accG[mi][ni][r];
            const float uu = accU[mi][ni][r];
            const float a = gg / (1.0f + __expf(-gg)) * uu;
            act[((size_t)e * 512 + m) * 2048 + n0 + ni * 16 + lr] = bf16_rne(a);
          }
        }
      }
    }
  }
}

// ---------- MoE pass 2 (BK=128, 8 steps, split-K=2): ob_part = act @ Wd ----------
// grid 512: e = bx&7, nt = (bx>>3)&31, kc = bx>>8. BM=512, BN=32, K-slice 1024.
__global__ __launch_bounds__(256, 2) void moe_mlp2_kernel(
    const unsigned short* __restrict__ act, const float* __restrict__ Wd,
    const int* __restrict__ cnt, float* __restrict__ ob) {
  const int bx = blockIdx.x;
  const int e = bx & 7;
  const int rr = bx >> 3;
  const int nt = rr & 31, kc = rr >> 5;
  const int n0 = nt * 32;
  const int ce = cnt[e];
  if (ce <= 0) return;
  __shared__ alignas(16) unsigned short BsL[2][32][136];
  const int tid = threadIdx.x;
  const int w = tid >> 6, l = tid & 63;
  const int lr = l & 15, lg = l >> 4;
  const int wc = tid & 31, kq = tid >> 5;
  const unsigned short* actE = act + (size_t)e * 512 * 2048 + (size_t)kc * 1024;
  const float* WdE = Wd + (size_t)e * 2048 * 1024
                     + (size_t)(kc * 1024 + kq * 16) * 1024 + n0 + wc;
  float* obE = ob + (size_t)kc * 8 * 512 * 1024;

  f32x4 acc[8][2];
#pragma unroll
  for (int mi = 0; mi < 8; ++mi)
#pragma unroll
    for (int ni = 0; ni < 2; ++ni) acc[mi][ni] = (f32x4){0.f, 0.f, 0.f, 0.f};

  float wdr[16];
  {
    float td[16];
#pragma unroll
    for (int j = 0; j < 16; ++j) td[j] = WdE[(size_t)j * 1024];
    u16x8 da, db;
#pragma unroll
    for (int j = 0; j < 8; ++j) { da[j] = bf16_rne(td[j]); db[j] = bf16_rne(td[j + 8]); }
    *reinterpret_cast<u16x8*>(&BsL[0][wc][kq * 16])     = da;
    *reinterpret_cast<u16x8*>(&BsL[0][wc][kq * 16 + 8]) = db;
  }
#pragma unroll
  for (int j = 0; j < 16; ++j) wdr[j] = WdE[(size_t)(128 + j) * 1024];
  __syncthreads();

  for (int t = 0; t < 8; ++t) {
    const int cur = t & 1;
    bfrag bf2[2][4];
#pragma unroll
    for (int ni = 0; ni < 2; ++ni)
#pragma unroll
      for (int kf = 0; kf < 4; ++kf)
        bf2[ni][kf] = *reinterpret_cast<const bfrag*>(&BsL[cur][ni * 16 + lr][kf * 32 + lg * 8]);
    u16x8 da, db;
    if (t < 7) {
#pragma unroll
      for (int j = 0; j < 8; ++j) { da[j] = bf16_rne(wdr[j]); db[j] = bf16_rne(wdr[j + 8]); }
    }
    if (t < 6) {
      const size_t kb = (size_t)(t + 2) * 128;
#pragma unroll
      for (int j = 0; j < 16; ++j) wdr[j] = WdE[(kb + j) * 1024];
    }
    const int kA = t * 128 + lg * 8;
#pragma unroll
    for (int mi = 0; mi < 8; ++mi) {
      const int row0 = (mi * 4 + w) * 16;
      if (row0 < ce) {
        const unsigned short* ap = &actE[(size_t)(row0 + lr) * 2048 + kA];
        const bfrag a0 = *reinterpret_cast<const bfrag*>(ap);
        const bfrag a1 = *reinterpret_cast<const bfrag*>(ap + 32);
        const bfrag a2 = *reinterpret_cast<const bfrag*>(ap + 64);
        const bfrag a3 = *reinterpret_cast<const bfrag*>(ap + 96);
#pragma unroll
        for (int ni = 0; ni < 2; ++ni) {
          acc[mi][ni] = __builtin_amdgcn_mfma_f32_16x16x32_bf16(a0, bf2[ni][0], acc[mi][ni], 0, 0, 0);
          acc[mi][ni] = __builtin_amdgcn_mfma_f32_16x16x32_bf16(a1, bf2[ni][1], acc[mi][ni], 0, 0, 0);
          acc[mi][ni] = __builtin_amdgcn_mfma_f32_16x16x32_bf16(a2, bf2[ni][2], acc[mi][ni], 0, 0, 0);
          acc[mi][ni] = __builtin_amdgcn_mfma_f32_16x16x32_bf16(a3, bf2[ni][3], acc[mi][ni], 0, 0, 0);
        }
      }
    }
    if (t < 7) {
      *reinterpret_cast<u16x8*>(&BsL[cur ^ 1][wc][kq * 16])     = da;
      *reinterpret_cast<u16x8*>(&BsL[cur ^ 1][wc][kq * 16 + 8]) = db;
    }
    __syncthreads();
  }
#pragma unroll
  for (int mi = 0; mi < 8; ++mi) {
    const int row0 = (mi * 4 + w) * 16;
    if (row0 < ce) {
#pragma unroll
      for (int r = 0; r < 4; ++r) {
        const int m = row0 + lg * 4 + r;
        if (m < ce) {
#pragma unroll
          for (int ni = 0; ni < 2; ++ni)
            obE[((size_t)e * 512 + m) * 1024 + n0 + ni * 16 + lr] = acc[mi][ni][r];
        }
      }
    }
  }
}

// ---------- combine: out += sum_k gate * (ob0+ob1)[e_k][slot_k] ----------
__global__ __launch_bounds__(256) void combine_kernel(
    const float* __restrict__ ob, const int* __restrict__ eidx,
    const float* __restrict__ egate, const int* __restrict__ entry_slot,
    float* __restrict__ out) {
  const int t = blockIdx.x;
  const int d = threadIdx.x * 4;
  const size_t half = (size_t)8 * 512 * 1024;
  float4 o4 = *reinterpret_cast<float4*>(&out[(size_t)t * 1024 + d]);
#pragma unroll
  for (int kk = 0; kk < 2; ++kk) {
    const int i = t * 2 + kk;
    const int s = entry_slot[i];
    if (s >= 0) {
      const int e = eidx[i];
      const float g = egate[i];
      const size_t base = ((size_t)e * 512 + s) * 1024 + d;
      const float4 c0 = *reinterpret_cast<const float4*>(&ob[base]);
      const float4 c1 = *reinterpret_cast<const float4*>(&ob[half + base]);
      o4.x += g * (c0.x + c1.x); o4.y += g * (c0.y + c1.y);
      o4.z += g * (c0.z + c1.z); o4.w += g * (c0.w + c1.w);
    }
  }
  *reinterpret_cast<float4*>(&out[(size_t)t * 1024 + d]) = o4;
}

extern "C" void kernel_launch(void* const* d_in, const int* in_sizes, int n_in,
                              void* d_out, int out_size, void* d_ws, size_t ws_size,
                              hipStream_t stream) {
  const float* hidden = (const float*)d_in[0];
  const int* posids  = (const int*)d_in[1];
  const float* ln1w  = (const float*)d_in[2];
  const float* ln2w  = (const float*)d_in[3];
  const float* Wq    = (const float*)d_in[4];
  const float* Wk    = (const float*)d_in[5];
  const float* Wv    = (const float*)d_in[6];
  const float* Wo    = (const float*)d_in[7];
  const float* Wr    = (const float*)d_in[8];
  const float* Wg    = (const float*)d_in[9];
  const float* Wu    = (const float*)d_in[10];
  const float* Wd    = (const float*)d_in[11];
  float* out = (float*)d_out;

  char* p = (char*)d_ws;
  auto alloc = [&](size_t bytes) { char* r = p; p += (bytes + 255) & ~(size_t)255; return r; };
  float* qb   = (float*)alloc((size_t)1024 * 1024 * 4);
  float* kb   = (float*)alloc((size_t)1024 * 256 * 4);
  float* vb   = (float*)alloc((size_t)1024 * 256 * 4);
  float* h2   = (float*)alloc((size_t)1024 * 1024 * 4);
  unsigned short* act = (unsigned short*)alloc((size_t)8 * 512 * 2048 * 2);
  float* obuf = (float*)alloc((size_t)2 * 8 * 512 * 1024 * 4);
  int* eidx   = (int*)alloc(2048 * 4);
  float* egate = (float*)alloc(2048 * 4);
  int* cnt    = (int*)alloc(8 * 4);
  int* slot_token = (int*)alloc((size_t)8 * 512 * 4);
  int* entry_slot = (int*)alloc(2048 * 4);
  float* cosT = (float*)alloc((size_t)1024 * 32 * 4);
  float* sinT = (float*)alloc((size_t)1024 * 32 * 4);
  unsigned short* Kp1 = (unsigned short*)alloc((size_t)4 * 1024 * 64 * 2);
  unsigned short* Kp2 = (unsigned short*)alloc((size_t)4 * 1024 * 64 * 2);
  unsigned short* Vp1 = (unsigned short*)alloc((size_t)4 * 1024 * 64 * 2);
  unsigned short* Vp2 = (unsigned short*)alloc((size_t)4 * 1024 * 64 * 2);
  unsigned short* xbf = (unsigned short*)alloc((size_t)8 * 512 * 1024 * 2);
  // split-3 planes
  const size_t MK = (size_t)1024 * 1024;
  unsigned short* h1s[3], *aos[3], *wqt[3], *wkt[3], *wvt[3], *wot[3];
  for (int s = 0; s < 3; ++s) h1s[s] = (unsigned short*)alloc(MK * 2);
  for (int s = 0; s < 3; ++s) aos[s] = (unsigned short*)alloc(MK * 2);
  for (int s = 0; s < 3; ++s) wqt[s] = (unsigned short*)alloc(MK * 2);
  for (int s = 0; s < 3; ++s) wkt[s] = (unsigned short*)alloc((size_t)256 * 1024 * 2);
  for (int s = 0; s < 3; ++s) wvt[s] = (unsigned short*)alloc((size_t)256 * 1024 * 2);
  for (int s = 0; s < 3; ++s) wot[s] = (unsigned short*)alloc(MK * 2);

  rope_table_kernel<<<128, 256, 0, stream>>>(posids, cosT, sinT);
  split3t_all_kernel<<<2560, 256, 0, stream>>>(Wq, Wk, Wv, Wo,
      wqt[0], wqt[1], wqt[2], wkt[0], wkt[1], wkt[2],
      wvt[0], wvt[1], wvt[2], wot[0], wot[1], wot[2]);

  ln_split3_kernel<<<1024, 256, 0, stream>>>(hidden, ln1w, h1s[0], h1s[1], h1s[2]);
  gemm_qkv_kernel<<<dim3(16, 24), 256, 0, stream>>>(h1s[0], h1s[1], h1s[2],
      wqt[0], wqt[1], wqt[2], wkt[0], wkt[1], wkt[2], wvt[0], wvt[1], wvt[2],
      qb, kb, vb);
  prep_kv_kernel<<<1024, 256, 0, stream>>>(kb, vb, cosT, sinT, Kp1, Kp2, Vp1, Vp2);
  attn_kernel<<<dim3(16, 16), 256, 0, stream>>>(qb, cosT, sinT, Kp1, Kp2, Vp1, Vp2,
      aos[0], aos[1], aos[2]);
  gemm_ps_kernel<<<dim3(16, 16), 256, 0, stream>>>(aos[0], aos[1], aos[2],
      wot[0], wot[1], wot[2], out, hidden, 1024, 1024, 0);
  ln_kernel<<<1024, 256, 0, stream>>>(out, ln2w, h2);
  router_kernel<<<1024, 64, 0, stream>>>(h2, Wr, eidx, egate);
  dispatch_kernel<<<1, 256, 0, stream>>>(eidx, cnt, slot_token, entry_slot);
  moe_xbf_kernel<<<4096, 256, 0, stream>>>(h2, cnt, slot_token, xbf);
  moe_mlp1_kernel<<<512, 256, 0, stream>>>(xbf, Wg, Wu, cnt, act);
  moe_mlp2_kernel<<<512, 256, 0, stream>>>(act, Wd, cnt, obuf);
  combine_kernel<<<1024, 256, 0, stream>>>(obuf, eidx, egate, entry_slot, out);
}

// Round 15
// 296.740 us; speedup vs baseline: 1.0902x; 1.0902x over previous
//
#include <hip/hip_runtime.h>
#include <math.h>

typedef __attribute__((ext_vector_type(8))) short bfrag;   // 8 x bf16 bits
typedef __attribute__((ext_vector_type(8))) unsigned short u16x8;
typedef __attribute__((ext_vector_type(4))) float f32x4;   // MFMA accumulator

// ---------- bf16 helpers ----------
__device__ __forceinline__ unsigned short bf16_rne(float f) {
  unsigned int u = __float_as_uint(f);
  u += 0x7FFFu + ((u >> 16) & 1u);
  return (unsigned short)(u >> 16);
}
__device__ __forceinline__ float bf16f(unsigned short h) {
  return __uint_as_float(((unsigned int)h) << 16);
}
__device__ __forceinline__ void split3(float x, unsigned short &o1, unsigned short &o2, unsigned short &o3) {
  o1 = bf16_rne(x);
  const float r1 = x - bf16f(o1);
  o2 = bf16_rne(r1);
  const float r2 = r1 - bf16f(o2);
  o3 = bf16_rne(r2);
}
__device__ __forceinline__ void split2(float x, unsigned short &o1, unsigned short &o2) {
  o1 = bf16_rne(x);
  o2 = bf16_rne(x - bf16f(o1));
}

// ---------- LayerNorm (row = 1024 f32) ----------
__global__ __launch_bounds__(256) void ln_kernel(const float* __restrict__ x,
                                                 const float* __restrict__ w,
                                                 float* __restrict__ out) {
  const int t = blockIdx.x;
  const int tid = threadIdx.x;
  const float4 v = *reinterpret_cast<const float4*>(&x[(size_t)t * 1024 + tid * 4]);
  float s = v.x + v.y + v.z + v.w;
  float ss = v.x * v.x + v.y * v.y + v.z * v.z + v.w * v.w;
#pragma unroll
  for (int off = 32; off; off >>= 1) {
    s += __shfl_xor(s, off);
    ss += __shfl_xor(ss, off);
  }
  __shared__ float red1[4], red2[4];
  if ((tid & 63) == 0) { red1[tid >> 6] = s; red2[tid >> 6] = ss; }
  __syncthreads();
  s = red1[0] + red1[1] + red1[2] + red1[3];
  ss = red2[0] + red2[1] + red2[2] + red2[3];
  const float mu = s * (1.0f / 1024.0f);
  const float var = ss * (1.0f / 1024.0f) - mu * mu;
  const float rstd = 1.0f / sqrtf(var + 1e-5f);
  const float4 wv = *reinterpret_cast<const float4*>(&w[tid * 4]);
  float4 o;
  o.x = (v.x - mu) * rstd * wv.x;
  o.y = (v.y - mu) * rstd * wv.y;
  o.z = (v.z - mu) * rstd * wv.z;
  o.w = (v.w - mu) * rstd * wv.w;
  *reinterpret_cast<float4*>(&out[(size_t)t * 1024 + tid * 4]) = o;
}

// ---------- fused LayerNorm -> split-3 bf16 planes ----------
__global__ __launch_bounds__(256) void ln_split3_kernel(
    const float* __restrict__ x, const float* __restrict__ w,
    unsigned short* __restrict__ d1, unsigned short* __restrict__ d2,
    unsigned short* __restrict__ d3) {
  const int t = blockIdx.x;
  const int tid = threadIdx.x;
  const float4 v = *reinterpret_cast<const float4*>(&x[(size_t)t * 1024 + tid * 4]);
  float s = v.x + v.y + v.z + v.w;
  float ss = v.x * v.x + v.y * v.y + v.z * v.z + v.w * v.w;
#pragma unroll
  for (int off = 32; off; off >>= 1) {
    s += __shfl_xor(s, off);
    ss += __shfl_xor(ss, off);
  }
  __shared__ float red1[4], red2[4];
  if ((tid & 63) == 0) { red1[tid >> 6] = s; red2[tid >> 6] = ss; }
  __syncthreads();
  s = red1[0] + red1[1] + red1[2] + red1[3];
  ss = red2[0] + red2[1] + red2[2] + red2[3];
  const float mu = s * (1.0f / 1024.0f);
  const float var = ss * (1.0f / 1024.0f) - mu * mu;
  const float rstd = 1.0f / sqrtf(var + 1e-5f);
  const float4 wv = *reinterpret_cast<const float4*>(&w[tid * 4]);
  float4 o;
  o.x = (v.x - mu) * rstd * wv.x;
  o.y = (v.y - mu) * rstd * wv.y;
  o.z = (v.z - mu) * rstd * wv.z;
  o.w = (v.w - mu) * rstd * wv.w;
  ushort4 a, b, c;
  split3(o.x, a.x, b.x, c.x);
  split3(o.y, a.y, b.y, c.y);
  split3(o.z, a.z, b.z, c.z);
  split3(o.w, a.w, b.w, c.w);
  const int i = t * 256 + tid;
  reinterpret_cast<ushort4*>(d1)[i] = a;
  reinterpret_cast<ushort4*>(d2)[i] = b;
  reinterpret_cast<ushort4*>(d3)[i] = c;
}

// ---------- fused: split-3 transposes of Wq/Wk/Wv/Wo + RoPE table ----------
// blocks 0..2559: weight transpose tiles; blocks 2560..2687: rope table
__global__ __launch_bounds__(256) void split3t_all_kernel(
    const float* __restrict__ Wq, const float* __restrict__ Wk,
    const float* __restrict__ Wv, const float* __restrict__ Wo,
    const int* __restrict__ posids, float* __restrict__ cosT, float* __restrict__ sinT,
    unsigned short* __restrict__ q1, unsigned short* __restrict__ q2, unsigned short* __restrict__ q3,
    unsigned short* __restrict__ k1, unsigned short* __restrict__ k2, unsigned short* __restrict__ k3,
    unsigned short* __restrict__ v1, unsigned short* __restrict__ v2, unsigned short* __restrict__ v3,
    unsigned short* __restrict__ o1, unsigned short* __restrict__ o2, unsigned short* __restrict__ o3) {
  const int bid = blockIdx.x;
  if (bid >= 2560) {
    const int t = (bid - 2560) * 8 + (threadIdx.x >> 5);
    const int i = threadIdx.x & 31;
    const double ang = (double)posids[t] * pow(500000.0, -(double)i / 32.0);
    cosT[t * 32 + i] = (float)cos(ang);
    sinT[t * 32 + i] = (float)sin(ang);
    return;
  }
  __shared__ float tile[32][33];
  const float* src;
  unsigned short *d1, *d2, *d3;
  int N, local;
  if (bid < 1024)      { src = Wq; d1 = q1; d2 = q2; d3 = q3; N = 1024; local = bid; }
  else if (bid < 1280) { src = Wk; d1 = k1; d2 = k2; d3 = k3; N = 256;  local = bid - 1024; }
  else if (bid < 1536) { src = Wv; d1 = v1; d2 = v2; d3 = v3; N = 256;  local = bid - 1280; }
  else                 { src = Wo; d1 = o1; d2 = o2; d3 = o3; N = 1024; local = bid - 1536; }
  const int K = 1024;
  const int k0 = (local & 31) * 32, n0 = (local >> 5) * 32;
  const int tx = threadIdx.x & 31, ty = threadIdx.x >> 5;
#pragma unroll
  for (int i = 0; i < 4; ++i)
    tile[ty + i * 8][tx] = src[(size_t)(k0 + ty + i * 8) * N + n0 + tx];
  __syncthreads();
#pragma unroll
  for (int i = 0; i < 4; ++i) {
    const float v = tile[tx][ty + i * 8];
    unsigned short s1, s2, s3;
    split3(v, s1, s2, s3);
    const size_t o = (size_t)(n0 + ty + i * 8) * K + k0 + tx;
    d1[o] = s1; d2[o] = s2; d3[o] = s3;
  }
}

// ---------- shared pre-split GEMM body, 64x64 tile, 4 waves, 2x2 acc ----------
__device__ __forceinline__ void gemm64_body(
    const unsigned short* __restrict__ A1, const unsigned short* __restrict__ A2,
    const unsigned short* __restrict__ A3, const unsigned short* __restrict__ B1,
    const unsigned short* __restrict__ B2, const unsigned short* __restrict__ B3,
    float* __restrict__ C, const float* __restrict__ Res,
    int N, int K, int doclip, int m0, int n0) {
  __shared__ alignas(16) unsigned short As[3][64][40];
  __shared__ alignas(16) unsigned short Bs[3][64][40];
  const int tid = threadIdx.x;
  const int w = tid >> 6, l = tid & 63;
  const int wm = (w >> 1) * 32, wn = (w & 1) * 32;
  const int lr = l & 15, lg = l >> 4;
  const int arow = tid >> 2, kslot = tid & 3;   // row 0..63, 8-k slot 0..3

  const unsigned short* Ap[3] = {A1, A2, A3};
  const unsigned short* Bp[3] = {B1, B2, B3};

  f32x4 acc[2][2] = {{{0.f,0.f,0.f,0.f},{0.f,0.f,0.f,0.f}},
                     {{0.f,0.f,0.f,0.f},{0.f,0.f,0.f,0.f}}};

  for (int k0 = 0; k0 < K; k0 += 32) {
#pragma unroll
    for (int s = 0; s < 3; ++s) {
      *reinterpret_cast<u16x8*>(&As[s][arow][kslot * 8]) =
          *reinterpret_cast<const u16x8*>(&Ap[s][(size_t)(m0 + arow) * K + k0 + kslot * 8]);
      *reinterpret_cast<u16x8*>(&Bs[s][arow][kslot * 8]) =
          *reinterpret_cast<const u16x8*>(&Bp[s][(size_t)(n0 + arow) * K + k0 + kslot * 8]);
    }
    __syncthreads();
    bfrag af[2][3], bg[2][3];
#pragma unroll
    for (int mi = 0; mi < 2; ++mi)
#pragma unroll
      for (int s = 0; s < 3; ++s)
        af[mi][s] = *reinterpret_cast<const bfrag*>(&As[s][wm + mi * 16 + lr][lg * 8]);
#pragma unroll
    for (int ni = 0; ni < 2; ++ni)
#pragma unroll
      for (int s = 0; s < 3; ++s)
        bg[ni][s] = *reinterpret_cast<const bfrag*>(&Bs[s][wn + ni * 16 + lr][lg * 8]);
#pragma unroll
    for (int mi = 0; mi < 2; ++mi)
#pragma unroll
      for (int ni = 0; ni < 2; ++ni) {
        f32x4 c = acc[mi][ni];
        c = __builtin_amdgcn_mfma_f32_16x16x32_bf16(af[mi][2], bg[ni][0], c, 0, 0, 0);
        c = __builtin_amdgcn_mfma_f32_16x16x32_bf16(af[mi][1], bg[ni][1], c, 0, 0, 0);
        c = __builtin_amdgcn_mfma_f32_16x16x32_bf16(af[mi][0], bg[ni][2], c, 0, 0, 0);
        c = __builtin_amdgcn_mfma_f32_16x16x32_bf16(af[mi][1], bg[ni][0], c, 0, 0, 0);
        c = __builtin_amdgcn_mfma_f32_16x16x32_bf16(af[mi][0], bg[ni][1], c, 0, 0, 0);
        c = __builtin_amdgcn_mfma_f32_16x16x32_bf16(af[mi][0], bg[ni][0], c, 0, 0, 0);
        acc[mi][ni] = c;
      }
    __syncthreads();
  }
#pragma unroll
  for (int mi = 0; mi < 2; ++mi)
#pragma unroll
    for (int ni = 0; ni < 2; ++ni)
#pragma unroll
      for (int r = 0; r < 4; ++r) {
        const int row = m0 + wm + mi * 16 + lg * 4 + r;
        const int col = n0 + wn + ni * 16 + lr;
        float vv = acc[mi][ni][r];
        if (doclip) vv = fminf(fmaxf(vv, -8.0f), 8.0f);
        if (Res) vv += Res[(size_t)row * N + col];
        C[(size_t)row * N + col] = vv;
      }
}

// generic pre-split GEMM (used for Wo): grid (M/64, N/64)
__global__ __launch_bounds__(256) void gemm_ps_kernel(
    const unsigned short* __restrict__ A1, const unsigned short* __restrict__ A2,
    const unsigned short* __restrict__ A3, const unsigned short* __restrict__ B1,
    const unsigned short* __restrict__ B2, const unsigned short* __restrict__ B3,
    float* __restrict__ C, const float* __restrict__ Res,
    int N, int K, int doclip) {
  gemm64_body(A1, A2, A3, B1, B2, B3, C, Res, N, K, doclip,
              blockIdx.x * 64, blockIdx.y * 64);
}

// fused Q/K/V GEMM: blockIdx.y 0..15 -> Wq, 16..19 -> Wk, 20..23 -> Wv
__global__ __launch_bounds__(256) void gemm_qkv_kernel(
    const unsigned short* __restrict__ A1, const unsigned short* __restrict__ A2,
    const unsigned short* __restrict__ A3,
    const unsigned short* __restrict__ Q1, const unsigned short* __restrict__ Q2,
    const unsigned short* __restrict__ Q3,
    const unsigned short* __restrict__ K1, const unsigned short* __restrict__ K2,
    const unsigned short* __restrict__ K3,
    const unsigned short* __restrict__ V1, const unsigned short* __restrict__ V2,
    const unsigned short* __restrict__ V3,
    float* __restrict__ qb, float* __restrict__ kb, float* __restrict__ vb) {
  const int by = blockIdx.y;
  const unsigned short *B1, *B2, *B3;
  float* C;
  int N, n0;
  if (by < 16)      { B1 = Q1; B2 = Q2; B3 = Q3; C = qb; N = 1024; n0 = by * 64; }
  else if (by < 20) { B1 = K1; B2 = K2; B3 = K3; C = kb; N = 256;  n0 = (by - 16) * 64; }
  else              { B1 = V1; B2 = V2; B3 = V3; C = vb; N = 256;  n0 = (by - 20) * 64; }
  gemm64_body(A1, A2, A3, B1, B2, B3, C, nullptr, N, 1024, 1, blockIdx.x * 64, n0);
}

// ---------- prep: fused k-RoPE + split-2 bf16 K (row-major) and V (transposed) ----------
__global__ __launch_bounds__(256) void prep_kv_kernel(
    const float* __restrict__ k, const float* __restrict__ v,
    const float* __restrict__ cosT, const float* __restrict__ sinT,
    unsigned short* __restrict__ Kp1, unsigned short* __restrict__ Kp2,
    unsigned short* __restrict__ Vp1, unsigned short* __restrict__ Vp2) {
  const int key = blockIdx.x;          // 0..1023
  const int kvh = threadIdx.x >> 6;    // 0..3
  const int d = threadIdx.x & 63;
  const int dd = d & 31;
  const float* kbase = &k[((size_t)key * 4 + kvh) * 64];
  const float c = cosT[key * 32 + dd], s = sinT[key * 32 + dd];
  const float u1 = kbase[dd], u2 = kbase[dd + 32];
  const float kk = (d < 32) ? (u1 * c - u2 * s) : (u2 * c + u1 * s);
  const float vv = v[((size_t)key * 4 + kvh) * 64 + d];
  unsigned short a1, a2, b1, b2;
  split2(kk, a1, a2);
  split2(vv, b1, b2);
  const size_t ki = ((size_t)kvh * 1024 + key) * 64 + d;
  Kp1[ki] = a1; Kp2[ki] = a2;
  const size_t vi = ((size_t)kvh * 64 + d) * 1024 + key;
  Vp1[vi] = b1; Vp2[vi] = b2;
}

// ---------- causal GQA flash attention, split-2 bf16 MFMA ----------
// q-RoPE fused into the Q-fragment load; epilogue writes split-3 planes
__global__ __launch_bounds__(256) void attn_kernel(
    const float* __restrict__ q,
    const float* __restrict__ cosT, const float* __restrict__ sinT,
    const unsigned short* __restrict__ Kp1, const unsigned short* __restrict__ Kp2,
    const unsigned short* __restrict__ Vp1, const unsigned short* __restrict__ Vp2,
    unsigned short* __restrict__ o1, unsigned short* __restrict__ o2,
    unsigned short* __restrict__ o3) {
  const int qt = blockIdx.x, h = blockIdx.y, kvh = h >> 2;
  __shared__ unsigned short Ks1[64][72], Ks2[64][72], Vt1[64][72], Vt2[64][72];
  __shared__ unsigned short Ps1[4][16][72], Ps2[4][16][72];
  const int tid = threadIdx.x;
  const int w = tid >> 6, l = tid & 63;
  const int lr = l & 15, lg = l >> 4;

  bfrag aq1[2], aq2[2];
  {
    const int tq = qt * 64 + w * 16 + lr;
    const float* qrow = &q[((size_t)tq * 16 + h) * 64];
    const float4 f00 = *reinterpret_cast<const float4*>(qrow + lg * 8);
    const float4 f01 = *reinterpret_cast<const float4*>(qrow + lg * 8 + 4);
    const float4 f10 = *reinterpret_cast<const float4*>(qrow + 32 + lg * 8);
    const float4 f11 = *reinterpret_cast<const float4*>(qrow + 32 + lg * 8 + 4);
    const float x0[8] = {f00.x, f00.y, f00.z, f00.w, f01.x, f01.y, f01.z, f01.w};
    const float x1[8] = {f10.x, f10.y, f10.z, f10.w, f11.x, f11.y, f11.z, f11.w};
#pragma unroll
    for (int j = 0; j < 8; ++j) {
      const float c = cosT[tq * 32 + lg * 8 + j];
      const float s = sinT[tq * 32 + lg * 8 + j];
      const float r0 = x0[j] * c - x1[j] * s;
      const float r1 = x1[j] * c + x0[j] * s;
      unsigned short p1, p2;
      split2(r0 * 0.125f, p1, p2);
      aq1[0][j] = (short)p1; aq2[0][j] = (short)p2;
      split2(r1 * 0.125f, p1, p2);
      aq1[1][j] = (short)p1; aq2[1][j] = (short)p2;
    }
  }

  f32x4 accO[4] = {{0.f,0.f,0.f,0.f},{0.f,0.f,0.f,0.f},{0.f,0.f,0.f,0.f},{0.f,0.f,0.f,0.f}};
  float mrun[4] = {-INFINITY, -INFINITY, -INFINITY, -INFINITY};
  float lrun[4] = {0.f, 0.f, 0.f, 0.f};

  for (int ti = 0; ti <= qt; ++ti) {
    const int s0 = ti * 64;
    {
      const size_t kbase = ((size_t)kvh * 1024 + s0 + l) * 64 + w * 16;
      *reinterpret_cast<u16x8*>(&Ks1[l][w * 16])     = *reinterpret_cast<const u16x8*>(&Kp1[kbase]);
      *reinterpret_cast<u16x8*>(&Ks1[l][w * 16 + 8]) = *reinterpret_cast<const u16x8*>(&Kp1[kbase + 8]);
      *reinterpret_cast<u16x8*>(&Ks2[l][w * 16])     = *reinterpret_cast<const u16x8*>(&Kp2[kbase]);
      *reinterpret_cast<u16x8*>(&Ks2[l][w * 16 + 8]) = *reinterpret_cast<const u16x8*>(&Kp2[kbase + 8]);
      const size_t vbase = ((size_t)kvh * 64 + l) * 1024 + s0 + w * 16;
      *reinterpret_cast<u16x8*>(&Vt1[l][w * 16])     = *reinterpret_cast<const u16x8*>(&Vp1[vbase]);
      *reinterpret_cast<u16x8*>(&Vt1[l][w * 16 + 8]) = *reinterpret_cast<const u16x8*>(&Vp1[vbase + 8]);
      *reinterpret_cast<u16x8*>(&Vt2[l][w * 16])     = *reinterpret_cast<const u16x8*>(&Vp2[vbase]);
      *reinterpret_cast<u16x8*>(&Vt2[l][w * 16 + 8]) = *reinterpret_cast<const u16x8*>(&Vp2[vbase + 8]);
    }
    __syncthreads();

    f32x4 accS[4] = {{0.f,0.f,0.f,0.f},{0.f,0.f,0.f,0.f},{0.f,0.f,0.f,0.f},{0.f,0.f,0.f,0.f}};
#pragma unroll
    for (int ks = 0; ks < 2; ++ks) {
      const int koff = ks * 32 + lg * 8;
#pragma unroll
      for (int ni = 0; ni < 4; ++ni) {
        const bfrag b1 = *reinterpret_cast<const bfrag*>(&Ks1[ni * 16 + lr][koff]);
        const bfrag b2 = *reinterpret_cast<const bfrag*>(&Ks2[ni * 16 + lr][koff]);
        f32x4 c = accS[ni];
        c = __builtin_amdgcn_mfma_f32_16x16x32_bf16(aq1[ks], b2, c, 0, 0, 0);
        c = __builtin_amdgcn_mfma_f32_16x16x32_bf16(aq2[ks], b1, c, 0, 0, 0);
        c = __builtin_amdgcn_mfma_f32_16x16x32_bf16(aq1[ks], b1, c, 0, 0, 0);
        accS[ni] = c;
      }
    }
    if (ti == qt) {
      const int rowb = w * 16 + lg * 4;
#pragma unroll
      for (int ni = 0; ni < 4; ++ni)
#pragma unroll
        for (int r = 0; r < 4; ++r)
          if (ni * 16 + lr > rowb + r) accS[ni][r] = -INFINITY;
    }
    float alpha[4];
#pragma unroll
    for (int r = 0; r < 4; ++r) {
      float tm = fmaxf(fmaxf(accS[0][r], accS[1][r]), fmaxf(accS[2][r], accS[3][r]));
      tm = fmaxf(tm, __shfl_xor(tm, 1));
      tm = fmaxf(tm, __shfl_xor(tm, 2));
      tm = fmaxf(tm, __shfl_xor(tm, 4));
      tm = fmaxf(tm, __shfl_xor(tm, 8));
      const float mnew = fmaxf(mrun[r], tm);
      alpha[r] = __expf(mrun[r] - mnew);
      mrun[r] = mnew;
      float ps = 0.f;
#pragma unroll
      for (int ni = 0; ni < 4; ++ni) {
        const float pv = __expf(accS[ni][r] - mnew);
        accS[ni][r] = pv;
        ps += pv;
      }
      ps += __shfl_xor(ps, 1);
      ps += __shfl_xor(ps, 2);
      ps += __shfl_xor(ps, 4);
      ps += __shfl_xor(ps, 8);
      lrun[r] = lrun[r] * alpha[r] + ps;
    }
#pragma unroll
    for (int ni = 0; ni < 4; ++ni)
#pragma unroll
      for (int r = 0; r < 4; ++r) {
        const float pv = accS[ni][r];
        unsigned short p1, p2;
        split2(pv, p1, p2);
        Ps1[w][lg * 4 + r][ni * 16 + lr] = p1;
        Ps2[w][lg * 4 + r][ni * 16 + lr] = p2;
      }
#pragma unroll
    for (int ni = 0; ni < 4; ++ni)
#pragma unroll
      for (int r = 0; r < 4; ++r) accO[ni][r] *= alpha[r];

    asm volatile("s_waitcnt lgkmcnt(0)" ::: "memory");

#pragma unroll
    for (int kk = 0; kk < 2; ++kk) {
      const int koff = kk * 32 + lg * 8;
      const bfrag pa1 = *reinterpret_cast<const bfrag*>(&Ps1[w][lr][koff]);
      const bfrag pa2 = *reinterpret_cast<const bfrag*>(&Ps2[w][lr][koff]);
#pragma unroll
      for (int ni = 0; ni < 4; ++ni) {
        const bfrag vb1 = *reinterpret_cast<const bfrag*>(&Vt1[ni * 16 + lr][koff]);
        const bfrag vb2 = *reinterpret_cast<const bfrag*>(&Vt2[ni * 16 + lr][koff]);
        f32x4 c = accO[ni];
        c = __builtin_amdgcn_mfma_f32_16x16x32_bf16(pa1, vb2, c, 0, 0, 0);
        c = __builtin_amdgcn_mfma_f32_16x16x32_bf16(pa2, vb1, c, 0, 0, 0);
        c = __builtin_amdgcn_mfma_f32_16x16x32_bf16(pa1, vb1, c, 0, 0, 0);
        accO[ni] = c;
      }
    }
    __syncthreads();
  }

  const int tqo = qt * 64 + w * 16 + lg * 4;
#pragma unroll
  for (int r = 0; r < 4; ++r) {
    const float inv = 1.0f / lrun[r];
#pragma unroll
    for (int ni = 0; ni < 4; ++ni) {
      const size_t oi = (size_t)(tqo + r) * 1024 + h * 64 + ni * 16 + lr;
      unsigned short s1, s2, s3;
      split3(accO[ni][r] * inv, s1, s2, s3);
      o1[oi] = s1; o2[oi] = s2; o3[oi] = s3;
    }
  }
}

// ---------- router: top-2 of softmax(h2 @ Wr) ----------
__global__ __launch_bounds__(64) void router_kernel(const float* __restrict__ h2,
                                                    const float* __restrict__ Wr,
                                                    int* __restrict__ eidx,
                                                    float* __restrict__ egate) {
  const int t = blockIdx.x;
  const int l = threadIdx.x;
  float p[8];
#pragma unroll
  for (int e = 0; e < 8; ++e) p[e] = 0.f;
  for (int d = l; d < 1024; d += 64) {
    const float x = h2[(size_t)t * 1024 + d];
    const float4 w0 = *reinterpret_cast<const float4*>(&Wr[d * 8]);
    const float4 w1 = *reinterpret_cast<const float4*>(&Wr[d * 8 + 4]);
    p[0] += x * w0.x; p[1] += x * w0.y; p[2] += x * w0.z; p[3] += x * w0.w;
    p[4] += x * w1.x; p[5] += x * w1.y; p[6] += x * w1.z; p[7] += x * w1.w;
  }
#pragma unroll
  for (int off = 32; off; off >>= 1) {
#pragma unroll
    for (int e = 0; e < 8; ++e) p[e] += __shfl_xor(p[e], off);
  }
  if (l == 0) {
    int i0 = 0; float b0 = p[0];
#pragma unroll
    for (int e = 1; e < 8; ++e) if (p[e] > b0) { b0 = p[e]; i0 = e; }
    int i1 = -1; float b1 = -INFINITY;
#pragma unroll
    for (int e = 0; e < 8; ++e) if (e != i0 && p[e] > b1) { b1 = p[e]; i1 = e; }
    const float ex = expf(b1 - b0);
    eidx[t * 2] = i0; eidx[t * 2 + 1] = i1;
    egate[t * 2] = 1.0f / (1.0f + ex);
    egate[t * 2 + 1] = ex / (1.0f + ex);
  }
}

// ---------- dispatch: replicate jnp cumsum slot assignment ----------
__global__ __launch_bounds__(256) void dispatch_kernel(
    const int* __restrict__ eidx, int* __restrict__ cnt,
    int* __restrict__ slot_token, int* __restrict__ entry_slot) {
  __shared__ unsigned char ef[2048];
  __shared__ unsigned short ch[256][8];
  const int tid = threadIdx.x;
  for (int i = tid; i < 2048; i += 256) ef[i] = (unsigned char)eidx[i];
  __syncthreads();
  int loc[8];
#pragma unroll
  for (int e = 0; e < 8; ++e) loc[e] = 0;
  const int base = tid * 8;
  for (int j = 0; j < 8; ++j) {
    const int ee = ef[base + j];
#pragma unroll
    for (int e = 0; e < 8; ++e) loc[e] += (ee == e);
  }
#pragma unroll
  for (int e = 0; e < 8; ++e) ch[tid][e] = (unsigned short)loc[e];
  __syncthreads();
  int pre[8];
#pragma unroll
  for (int e = 0; e < 8; ++e) pre[e] = 0;
  for (int t2 = 0; t2 < tid; ++t2) {
#pragma unroll
    for (int e = 0; e < 8; ++e) pre[e] += ch[t2][e];
  }
  if (tid == 255) {
#pragma unroll
    for (int e = 0; e < 8; ++e) cnt[e] = min(pre[e] + loc[e], 512);
  }
  for (int j = 0; j < 8; ++j) {
    const int i = base + j;
    const int ee = ef[i];
    int slot = 0;
#pragma unroll
    for (int e = 0; e < 8; ++e) {
      if (e == ee) { slot = pre[e]; pre[e] = pre[e] + 1; }
    }
    if (slot < 512) {
      slot_token[ee * 512 + slot] = i >> 1;
      entry_slot[i] = slot;
    } else {
      entry_slot[i] = -1;
    }
  }
}

// ---------- pre-convert dispatched tokens to bf16: xbf[e][slot][1024] ----------
__global__ __launch_bounds__(256) void moe_xbf_kernel(
    const float* __restrict__ h2, const int* __restrict__ cnt,
    const int* __restrict__ slot_token, unsigned short* __restrict__ xbf) {
  const int row = blockIdx.x;          // e*512 + slot
  const int e = row >> 9, slot = row & 511;
  const int tid = threadIdx.x;
  ushort4 o;
  if (slot < cnt[e]) {
    const int tok = slot_token[row];
    const float4 f = *reinterpret_cast<const float4*>(&h2[(size_t)tok * 1024 + tid * 4]);
    o = make_ushort4(bf16_rne(f.x), bf16_rne(f.y), bf16_rne(f.z), bf16_rne(f.w));
  } else {
    o = make_ushort4(0, 0, 0, 0);
  }
  *reinterpret_cast<ushort4*>(&xbf[(size_t)row * 1024 + tid * 4]) = o;
}

// ---------- MoE pass 1 (round-5 exact): act = silu(X@Wg)*(X@Wu) ----------
// grid 512 flat: e = bx&7 (expert->XCD), nt = bx>>3 (BN=32). BM=512 (whole expert).
__global__ __launch_bounds__(256, 2) void moe_mlp1_kernel(
    const unsigned short* __restrict__ xbf, const float* __restrict__ Wg,
    const float* __restrict__ Wu, const int* __restrict__ cnt,
    unsigned short* __restrict__ act) {
  const int bx = blockIdx.x;
  const int e = bx & 7, nt = bx >> 3;
  const int n0 = nt * 32;
  const int ce = cnt[e];
  if (ce <= 0) return;
  __shared__ alignas(16) unsigned short BgL[2][32][72], BuL[2][32][72];
  const int tid = threadIdx.x;
  const int w = tid >> 6, l = tid & 63;
  const int lr = l & 15, lg = l >> 4;
  const int wc = tid & 31, kq8 = tid >> 5;
  const float* WgE = Wg + (size_t)e * 1024 * 2048 + (size_t)kq8 * 8 * 2048 + n0 + wc;
  const float* WuE = Wu + (size_t)e * 1024 * 2048 + (size_t)kq8 * 8 * 2048 + n0 + wc;
  const unsigned short* xbE = xbf + (size_t)e * 512 * 1024;

  f32x4 accG[8][2], accU[8][2];
#pragma unroll
  for (int mi = 0; mi < 8; ++mi)
#pragma unroll
    for (int ni = 0; ni < 2; ++ni) {
      accG[mi][ni] = (f32x4){0.f, 0.f, 0.f, 0.f};
      accU[mi][ni] = (f32x4){0.f, 0.f, 0.f, 0.f};
    }

  float wgr[8], wur[8];
#pragma unroll
  for (int j = 0; j < 8; ++j) { wgr[j] = WgE[(size_t)j * 2048]; wur[j] = WuE[(size_t)j * 2048]; }
  {
    u16x8 g8, u8;
#pragma unroll
    for (int j = 0; j < 8; ++j) { g8[j] = bf16_rne(wgr[j]); u8[j] = bf16_rne(wur[j]); }
    *reinterpret_cast<u16x8*>(&BgL[0][wc][kq8 * 8]) = g8;
    *reinterpret_cast<u16x8*>(&BuL[0][wc][kq8 * 8]) = u8;
  }
#pragma unroll
  for (int j = 0; j < 8; ++j) { wgr[j] = WgE[(size_t)(64 + j) * 2048]; wur[j] = WuE[(size_t)(64 + j) * 2048]; }
  __syncthreads();

  for (int t = 0; t < 16; ++t) {
    const int cur = t & 1;
    bfrag bgf[2][2], buf2[2][2];
#pragma unroll
    for (int ni = 0; ni < 2; ++ni)
#pragma unroll
      for (int kf = 0; kf < 2; ++kf) {
        bgf[ni][kf]  = *reinterpret_cast<const bfrag*>(&BgL[cur][ni * 16 + lr][kf * 32 + lg * 8]);
        buf2[ni][kf] = *reinterpret_cast<const bfrag*>(&BuL[cur][ni * 16 + lr][kf * 32 + lg * 8]);
      }
    u16x8 g8, u8;
    if (t < 15) {
#pragma unroll
      for (int j = 0; j < 8; ++j) { g8[j] = bf16_rne(wgr[j]); u8[j] = bf16_rne(wur[j]); }
    }
    if (t < 14) {
      const size_t kb = (size_t)(t + 2) * 64;
#pragma unroll
      for (int j = 0; j < 8; ++j) { wgr[j] = WgE[(kb + j) * 2048]; wur[j] = WuE[(kb + j) * 2048]; }
    }
    const int kA = t * 64 + lg * 8;
#pragma unroll
    for (int mi = 0; mi < 8; ++mi) {
      const int row0 = (mi * 4 + w) * 16;   // wave-interleaved 16-row groups
      if (row0 < ce) {
        const unsigned short* ap = &xbE[(size_t)(row0 + lr) * 1024 + kA];
        const bfrag a0 = *reinterpret_cast<const bfrag*>(ap);
        const bfrag a1 = *reinterpret_cast<const bfrag*>(ap + 32);
#pragma unroll
        for (int ni = 0; ni < 2; ++ni) {
          accG[mi][ni] = __builtin_amdgcn_mfma_f32_16x16x32_bf16(a0, bgf[ni][0], accG[mi][ni], 0, 0, 0);
          accG[mi][ni] = __builtin_amdgcn_mfma_f32_16x16x32_bf16(a1, bgf[ni][1], accG[mi][ni], 0, 0, 0);
          accU[mi][ni] = __builtin_amdgcn_mfma_f32_16x16x32_bf16(a0, buf2[ni][0], accU[mi][ni], 0, 0, 0);
          accU[mi][ni] = __builtin_amdgcn_mfma_f32_16x16x32_bf16(a1, buf2[ni][1], accU[mi][ni], 0, 0, 0);
        }
      }
    }
    if (t < 15) {
      *reinterpret_cast<u16x8*>(&BgL[cur ^ 1][wc][kq8 * 8]) = g8;
      *reinterpret_cast<u16x8*>(&BuL[cur ^ 1][wc][kq8 * 8]) = u8;
    }
    __syncthreads();
  }
#pragma unroll
  for (int mi = 0; mi < 8; ++mi) {
    const int row0 = (mi * 4 + w) * 16;
    if (row0 < ce) {
#pragma unroll
      for (int r = 0; r < 4; ++r) {
        const int m = row0 + lg * 4 + r;
        if (m < ce) {
#pragma unroll
          for (int ni = 0; ni < 2; ++ni) {
            const float gg = accG[mi][ni][r];
            const float uu = accU[mi][ni][r];
            const float a = gg / (1.0f + __expf(-gg)) * uu;
            act[((size_t)e * 512 + m) * 2048 + n0 + ni * 16 + lr] = bf16_rne(a);
          }
        }
      }
    }
  }
}

// ---------- MoE pass 2 (round-5 exact, split-K=2): ob_part = act @ Wd ----------
// grid 512 flat: e = bx&7, nt = (bx>>3)&31, kc = bx>>8. BM=512, BN=32, K-slice 1024.
__global__ __launch_bounds__(256, 2) void moe_mlp2_kernel(
    const unsigned short* __restrict__ act, const float* __restrict__ Wd,
    const int* __restrict__ cnt, float* __restrict__ ob) {
  const int bx = blockIdx.x;
  const int e = bx & 7;
  const int rr = bx >> 3;
  const int nt = rr & 31, kc = rr >> 5;
  const int n0 = nt * 32;
  const int ce = cnt[e];
  if (ce <= 0) return;
  __shared__ alignas(16) unsigned short BsL[2][32][72];
  const int tid = threadIdx.x;
  const int w = tid >> 6, l = tid & 63;
  const int lr = l & 15, lg = l >> 4;
  const int wc = tid & 31, kq8 = tid >> 5;
  const unsigned short* actE = act + (size_t)e * 512 * 2048 + (size_t)kc * 1024;
  const float* WdE = Wd + (size_t)e * 2048 * 1024 + (size_t)(kc * 1024 + kq8 * 8) * 1024 + n0 + wc;
  float* obE = ob + (size_t)kc * 8 * 512 * 1024;

  f32x4 acc[8][2];
#pragma unroll
  for (int mi = 0; mi < 8; ++mi)
#pragma unroll
    for (int ni = 0; ni < 2; ++ni) acc[mi][ni] = (f32x4){0.f, 0.f, 0.f, 0.f};

  float wdr[8];
#pragma unroll
  for (int j = 0; j < 8; ++j) wdr[j] = WdE[(size_t)j * 1024];
  {
    u16x8 d8;
#pragma unroll
    for (int j = 0; j < 8; ++j) d8[j] = bf16_rne(wdr[j]);
    *reinterpret_cast<u16x8*>(&BsL[0][wc][kq8 * 8]) = d8;
  }
#pragma unroll
  for (int j = 0; j < 8; ++j) wdr[j] = WdE[(size_t)(64 + j) * 1024];
  __syncthreads();

  for (int t = 0; t < 16; ++t) {
    const int cur = t & 1;
    bfrag bf2[2][2];
#pragma unroll
    for (int ni = 0; ni < 2; ++ni)
#pragma unroll
      for (int kf = 0; kf < 2; ++kf)
        bf2[ni][kf] = *reinterpret_cast<const bfrag*>(&BsL[cur][ni * 16 + lr][kf * 32 + lg * 8]);
    u16x8 d8;
    if (t < 15) {
#pragma unroll
      for (int j = 0; j < 8; ++j) d8[j] = bf16_rne(wdr[j]);
    }
    if (t < 14) {
      const size_t kb = (size_t)(t + 2) * 64;
#pragma unroll
      for (int j = 0; j < 8; ++j) wdr[j] = WdE[(kb + j) * 1024];
    }
    const int kA = t * 64 + lg * 8;
#pragma unroll
    for (int mi = 0; mi < 8; ++mi) {
      const int row0 = (mi * 4 + w) * 16;
      if (row0 < ce) {
        const unsigned short* ap = &actE[(size_t)(row0 + lr) * 2048 + kA];
        const bfrag a0 = *reinterpret_cast<const bfrag*>(ap);
        const bfrag a1 = *reinterpret_cast<const bfrag*>(ap + 32);
#pragma unroll
        for (int ni = 0; ni < 2; ++ni) {
          acc[mi][ni] = __builtin_amdgcn_mfma_f32_16x16x32_bf16(a0, bf2[ni][0], acc[mi][ni], 0, 0, 0);
          acc[mi][ni] = __builtin_amdgcn_mfma_f32_16x16x32_bf16(a1, bf2[ni][1], acc[mi][ni], 0, 0, 0);
        }
      }
    }
    if (t < 15) {
      *reinterpret_cast<u16x8*>(&BsL[cur ^ 1][wc][kq8 * 8]) = d8;
    }
    __syncthreads();
  }
#pragma unroll
  for (int mi = 0; mi < 8; ++mi) {
    const int row0 = (mi * 4 + w) * 16;
    if (row0 < ce) {
#pragma unroll
      for (int r = 0; r < 4; ++r) {
        const int m = row0 + lg * 4 + r;
        if (m < ce) {
#pragma unroll
          for (int ni = 0; ni < 2; ++ni)
            obE[((size_t)e * 512 + m) * 1024 + n0 + ni * 16 + lr] = acc[mi][ni][r];
        }
      }
    }
  }
}

// ---------- combine: out += sum_k gate * (ob0+ob1)[e_k][slot_k] ----------
__global__ __launch_bounds__(256) void combine_kernel(
    const float* __restrict__ ob, const int* __restrict__ eidx,
    const float* __restrict__ egate, const int* __restrict__ entry_slot,
    float* __restrict__ out) {
  const int t = blockIdx.x;
  const int d = threadIdx.x * 4;
  const size_t half = (size_t)8 * 512 * 1024;
  float4 o4 = *reinterpret_cast<float4*>(&out[(size_t)t * 1024 + d]);
#pragma unroll
  for (int kk = 0; kk < 2; ++kk) {
    const int i = t * 2 + kk;
    const int s = entry_slot[i];
    if (s >= 0) {
      const int e = eidx[i];
      const float g = egate[i];
      const size_t base = ((size_t)e * 512 + s) * 1024 + d;
      const float4 c0 = *reinterpret_cast<const float4*>(&ob[base]);
      const float4 c1 = *reinterpret_cast<const float4*>(&ob[half + base]);
      o4.x += g * (c0.x + c1.x); o4.y += g * (c0.y + c1.y);
      o4.z += g * (c0.z + c1.z); o4.w += g * (c0.w + c1.w);
    }
  }
  *reinterpret_cast<float4*>(&out[(size_t)t * 1024 + d]) = o4;
}

extern "C" void kernel_launch(void* const* d_in, const int* in_sizes, int n_in,
                              void* d_out, int out_size, void* d_ws, size_t ws_size,
                              hipStream_t stream) {
  const float* hidden = (const float*)d_in[0];
  const int* posids  = (const int*)d_in[1];
  const float* ln1w  = (const float*)d_in[2];
  const float* ln2w  = (const float*)d_in[3];
  const float* Wq    = (const float*)d_in[4];
  const float* Wk    = (const float*)d_in[5];
  const float* Wv    = (const float*)d_in[6];
  const float* Wo    = (const float*)d_in[7];
  const float* Wr    = (const float*)d_in[8];
  const float* Wg    = (const float*)d_in[9];
  const float* Wu    = (const float*)d_in[10];
  const float* Wd    = (const float*)d_in[11];
  float* out = (float*)d_out;

  char* p = (char*)d_ws;
  auto alloc = [&](size_t bytes) { char* r = p; p += (bytes + 255) & ~(size_t)255; return r; };
  float* qb   = (float*)alloc((size_t)1024 * 1024 * 4);
  float* kb   = (float*)alloc((size_t)1024 * 256 * 4);
  float* vb   = (float*)alloc((size_t)1024 * 256 * 4);
  float* h2   = (float*)alloc((size_t)1024 * 1024 * 4);
  unsigned short* act = (unsigned short*)alloc((size_t)8 * 512 * 2048 * 2);
  float* obuf = (float*)alloc((size_t)2 * 8 * 512 * 1024 * 4);
  int* eidx   = (int*)alloc(2048 * 4);
  float* egate = (float*)alloc(2048 * 4);
  int* cnt    = (int*)alloc(8 * 4);
  int* slot_token = (int*)alloc((size_t)8 * 512 * 4);
  int* entry_slot = (int*)alloc(2048 * 4);
  float* cosT = (float*)alloc((size_t)1024 * 32 * 4);
  float* sinT = (float*)alloc((size_t)1024 * 32 * 4);
  unsigned short* Kp1 = (unsigned short*)alloc((size_t)4 * 1024 * 64 * 2);
  unsigned short* Kp2 = (unsigned short*)alloc((size_t)4 * 1024 * 64 * 2);
  unsigned short* Vp1 = (unsigned short*)alloc((size_t)4 * 1024 * 64 * 2);
  unsigned short* Vp2 = (unsigned short*)alloc((size_t)4 * 1024 * 64 * 2);
  unsigned short* xbf = (unsigned short*)alloc((size_t)8 * 512 * 1024 * 2);
  // split-3 planes
  const size_t MK = (size_t)1024 * 1024;
  unsigned short* h1s[3], *aos[3], *wqt[3], *wkt[3], *wvt[3], *wot[3];
  for (int s = 0; s < 3; ++s) h1s[s] = (unsigned short*)alloc(MK * 2);
  for (int s = 0; s < 3; ++s) aos[s] = (unsigned short*)alloc(MK * 2);
  for (int s = 0; s < 3; ++s) wqt[s] = (unsigned short*)alloc(MK * 2);
  for (int s = 0; s < 3; ++s) wkt[s] = (unsigned short*)alloc((size_t)256 * 1024 * 2);
  for (int s = 0; s < 3; ++s) wvt[s] = (unsigned short*)alloc((size_t)256 * 1024 * 2);
  for (int s = 0; s < 3; ++s) wot[s] = (unsigned short*)alloc(MK * 2);

  split3t_all_kernel<<<2688, 256, 0, stream>>>(Wq, Wk, Wv, Wo, posids, cosT, sinT,
      wqt[0], wqt[1], wqt[2], wkt[0], wkt[1], wkt[2],
      wvt[0], wvt[1], wvt[2], wot[0], wot[1], wot[2]);

  ln_split3_kernel<<<1024, 256, 0, stream>>>(hidden, ln1w, h1s[0], h1s[1], h1s[2]);
  gemm_qkv_kernel<<<dim3(16, 24), 256, 0, stream>>>(h1s[0], h1s[1], h1s[2],
      wqt[0], wqt[1], wqt[2], wkt[0], wkt[1], wkt[2], wvt[0], wvt[1], wvt[2],
      qb, kb, vb);
  prep_kv_kernel<<<1024, 256, 0, stream>>>(kb, vb, cosT, sinT, Kp1, Kp2, Vp1, Vp2);
  attn_kernel<<<dim3(16, 16), 256, 0, stream>>>(qb, cosT, sinT, Kp1, Kp2, Vp1, Vp2,
      aos[0], aos[1], aos[2]);
  gemm_ps_kernel<<<dim3(16, 16), 256, 0, stream>>>(aos[0], aos[1], aos[2],
      wot[0], wot[1], wot[2], out, hidden, 1024, 1024, 0);
  ln_kernel<<<1024, 256, 0, stream>>>(out, ln2w, h2);
  router_kernel<<<1024, 64, 0, stream>>>(h2, Wr, eidx, egate);
  dispatch_kernel<<<1, 256, 0, stream>>>(eidx, cnt, slot_token, entry_slot);
  moe_xbf_kernel<<<4096, 256, 0, stream>>>(h2, cnt, slot_token, xbf);
  moe_mlp1_kernel<<<512, 256, 0, stream>>>(xbf, Wg, Wu, cnt, act);
  moe_mlp2_kernel<<<512, 256, 0, stream>>>(act, Wd, cnt, obuf);
  combine_kernel<<<1024, 256, 0, stream>>>(obuf, eidx, egate, entry_slot, out);
}

// Round 16
// 296.501 us; speedup vs baseline: 1.0911x; 1.0008x over previous
//
#include <hip/hip_runtime.h>
#include <math.h>

typedef __attribute__((ext_vector_type(8))) short bfrag;   // 8 x bf16 bits
typedef __attribute__((ext_vector_type(8))) unsigned short u16x8;
typedef __attribute__((ext_vector_type(4))) float f32x4;   // MFMA accumulator

// ---------- bf16 helpers ----------
__device__ __forceinline__ unsigned short bf16_rne(float f) {
  unsigned int u = __float_as_uint(f);
  u += 0x7FFFu + ((u >> 16) & 1u);
  return (unsigned short)(u >> 16);
}
__device__ __forceinline__ float bf16f(unsigned short h) {
  return __uint_as_float(((unsigned int)h) << 16);
}
__device__ __forceinline__ void split3(float x, unsigned short &o1, unsigned short &o2, unsigned short &o3) {
  o1 = bf16_rne(x);
  const float r1 = x - bf16f(o1);
  o2 = bf16_rne(r1);
  const float r2 = r1 - bf16f(o2);
  o3 = bf16_rne(r2);
}
__device__ __forceinline__ void split2(float x, unsigned short &o1, unsigned short &o2) {
  o1 = bf16_rne(x);
  o2 = bf16_rne(x - bf16f(o1));
}

// ---------- LayerNorm (row = 1024 f32) ----------
__global__ __launch_bounds__(256) void ln_kernel(const float* __restrict__ x,
                                                 const float* __restrict__ w,
                                                 float* __restrict__ out) {
  const int t = blockIdx.x;
  const int tid = threadIdx.x;
  const float4 v = *reinterpret_cast<const float4*>(&x[(size_t)t * 1024 + tid * 4]);
  float s = v.x + v.y + v.z + v.w;
  float ss = v.x * v.x + v.y * v.y + v.z * v.z + v.w * v.w;
#pragma unroll
  for (int off = 32; off; off >>= 1) {
    s += __shfl_xor(s, off);
    ss += __shfl_xor(ss, off);
  }
  __shared__ float red1[4], red2[4];
  if ((tid & 63) == 0) { red1[tid >> 6] = s; red2[tid >> 6] = ss; }
  __syncthreads();
  s = red1[0] + red1[1] + red1[2] + red1[3];
  ss = red2[0] + red2[1] + red2[2] + red2[3];
  const float mu = s * (1.0f / 1024.0f);
  const float var = ss * (1.0f / 1024.0f) - mu * mu;
  const float rstd = 1.0f / sqrtf(var + 1e-5f);
  const float4 wv = *reinterpret_cast<const float4*>(&w[tid * 4]);
  float4 o;
  o.x = (v.x - mu) * rstd * wv.x;
  o.y = (v.y - mu) * rstd * wv.y;
  o.z = (v.z - mu) * rstd * wv.z;
  o.w = (v.w - mu) * rstd * wv.w;
  *reinterpret_cast<float4*>(&out[(size_t)t * 1024 + tid * 4]) = o;
}

// ---------- fused LayerNorm -> split-3 bf16 planes ----------
__global__ __launch_bounds__(256) void ln_split3_kernel(
    const float* __restrict__ x, const float* __restrict__ w,
    unsigned short* __restrict__ d1, unsigned short* __restrict__ d2,
    unsigned short* __restrict__ d3) {
  const int t = blockIdx.x;
  const int tid = threadIdx.x;
  const float4 v = *reinterpret_cast<const float4*>(&x[(size_t)t * 1024 + tid * 4]);
  float s = v.x + v.y + v.z + v.w;
  float ss = v.x * v.x + v.y * v.y + v.z * v.z + v.w * v.w;
#pragma unroll
  for (int off = 32; off; off >>= 1) {
    s += __shfl_xor(s, off);
    ss += __shfl_xor(ss, off);
  }
  __shared__ float red1[4], red2[4];
  if ((tid & 63) == 0) { red1[tid >> 6] = s; red2[tid >> 6] = ss; }
  __syncthreads();
  s = red1[0] + red1[1] + red1[2] + red1[3];
  ss = red2[0] + red2[1] + red2[2] + red2[3];
  const float mu = s * (1.0f / 1024.0f);
  const float var = ss * (1.0f / 1024.0f) - mu * mu;
  const float rstd = 1.0f / sqrtf(var + 1e-5f);
  const float4 wv = *reinterpret_cast<const float4*>(&w[tid * 4]);
  float4 o;
  o.x = (v.x - mu) * rstd * wv.x;
  o.y = (v.y - mu) * rstd * wv.y;
  o.z = (v.z - mu) * rstd * wv.z;
  o.w = (v.w - mu) * rstd * wv.w;
  ushort4 a, b, c;
  split3(o.x, a.x, b.x, c.x);
  split3(o.y, a.y, b.y, c.y);
  split3(o.z, a.z, b.z, c.z);
  split3(o.w, a.w, b.w, c.w);
  const int i = t * 256 + tid;
  reinterpret_cast<ushort4*>(d1)[i] = a;
  reinterpret_cast<ushort4*>(d2)[i] = b;
  reinterpret_cast<ushort4*>(d3)[i] = c;
}

// ---------- fused: split-3 transposes of Wq/Wk/Wv/Wo + RoPE table ----------
// blocks 0..2559: weight transpose tiles; blocks 2560..2687: rope table
__global__ __launch_bounds__(256) void split3t_all_kernel(
    const float* __restrict__ Wq, const float* __restrict__ Wk,
    const float* __restrict__ Wv, const float* __restrict__ Wo,
    const int* __restrict__ posids, float* __restrict__ cosT, float* __restrict__ sinT,
    unsigned short* __restrict__ q1, unsigned short* __restrict__ q2, unsigned short* __restrict__ q3,
    unsigned short* __restrict__ k1, unsigned short* __restrict__ k2, unsigned short* __restrict__ k3,
    unsigned short* __restrict__ v1, unsigned short* __restrict__ v2, unsigned short* __restrict__ v3,
    unsigned short* __restrict__ o1, unsigned short* __restrict__ o2, unsigned short* __restrict__ o3) {
  const int bid = blockIdx.x;
  if (bid >= 2560) {
    const int t = (bid - 2560) * 8 + (threadIdx.x >> 5);
    const int i = threadIdx.x & 31;
    const double ang = (double)posids[t] * pow(500000.0, -(double)i / 32.0);
    cosT[t * 32 + i] = (float)cos(ang);
    sinT[t * 32 + i] = (float)sin(ang);
    return;
  }
  __shared__ float tile[32][33];
  const float* src;
  unsigned short *d1, *d2, *d3;
  int N, local;
  if (bid < 1024)      { src = Wq; d1 = q1; d2 = q2; d3 = q3; N = 1024; local = bid; }
  else if (bid < 1280) { src = Wk; d1 = k1; d2 = k2; d3 = k3; N = 256;  local = bid - 1024; }
  else if (bid < 1536) { src = Wv; d1 = v1; d2 = v2; d3 = v3; N = 256;  local = bid - 1280; }
  else                 { src = Wo; d1 = o1; d2 = o2; d3 = o3; N = 1024; local = bid - 1536; }
  const int K = 1024;
  const int k0 = (local & 31) * 32, n0 = (local >> 5) * 32;
  const int tx = threadIdx.x & 31, ty = threadIdx.x >> 5;
#pragma unroll
  for (int i = 0; i < 4; ++i)
    tile[ty + i * 8][tx] = src[(size_t)(k0 + ty + i * 8) * N + n0 + tx];
  __syncthreads();
#pragma unroll
  for (int i = 0; i < 4; ++i) {
    const float v = tile[tx][ty + i * 8];
    unsigned short s1, s2, s3;
    split3(v, s1, s2, s3);
    const size_t o = (size_t)(n0 + ty + i * 8) * K + k0 + tx;
    d1[o] = s1; d2[o] = s2; d3[o] = s3;
  }
}

// ---------- shared pre-split GEMM body, 64x64 tile, 4 waves, 2x2 acc ----------
__device__ __forceinline__ void gemm64_body(
    const unsigned short* __restrict__ A1, const unsigned short* __restrict__ A2,
    const unsigned short* __restrict__ A3, const unsigned short* __restrict__ B1,
    const unsigned short* __restrict__ B2, const unsigned short* __restrict__ B3,
    float* __restrict__ C, const float* __restrict__ Res,
    int N, int K, int doclip, int m0, int n0) {
  __shared__ alignas(16) unsigned short As[3][64][40];
  __shared__ alignas(16) unsigned short Bs[3][64][40];
  const int tid = threadIdx.x;
  const int w = tid >> 6, l = tid & 63;
  const int wm = (w >> 1) * 32, wn = (w & 1) * 32;
  const int lr = l & 15, lg = l >> 4;
  const int arow = tid >> 2, kslot = tid & 3;   // row 0..63, 8-k slot 0..3

  const unsigned short* Ap[3] = {A1, A2, A3};
  const unsigned short* Bp[3] = {B1, B2, B3};

  f32x4 acc[2][2] = {{{0.f,0.f,0.f,0.f},{0.f,0.f,0.f,0.f}},
                     {{0.f,0.f,0.f,0.f},{0.f,0.f,0.f,0.f}}};

  for (int k0 = 0; k0 < K; k0 += 32) {
#pragma unroll
    for (int s = 0; s < 3; ++s) {
      *reinterpret_cast<u16x8*>(&As[s][arow][kslot * 8]) =
          *reinterpret_cast<const u16x8*>(&Ap[s][(size_t)(m0 + arow) * K + k0 + kslot * 8]);
      *reinterpret_cast<u16x8*>(&Bs[s][arow][kslot * 8]) =
          *reinterpret_cast<const u16x8*>(&Bp[s][(size_t)(n0 + arow) * K + k0 + kslot * 8]);
    }
    __syncthreads();
    bfrag af[2][3], bg[2][3];
#pragma unroll
    for (int mi = 0; mi < 2; ++mi)
#pragma unroll
      for (int s = 0; s < 3; ++s)
        af[mi][s] = *reinterpret_cast<const bfrag*>(&As[s][wm + mi * 16 + lr][lg * 8]);
#pragma unroll
    for (int ni = 0; ni < 2; ++ni)
#pragma unroll
      for (int s = 0; s < 3; ++s)
        bg[ni][s] = *reinterpret_cast<const bfrag*>(&Bs[s][wn + ni * 16 + lr][lg * 8]);
#pragma unroll
    for (int mi = 0; mi < 2; ++mi)
#pragma unroll
      for (int ni = 0; ni < 2; ++ni) {
        f32x4 c = acc[mi][ni];
        c = __builtin_amdgcn_mfma_f32_16x16x32_bf16(af[mi][2], bg[ni][0], c, 0, 0, 0);
        c = __builtin_amdgcn_mfma_f32_16x16x32_bf16(af[mi][1], bg[ni][1], c, 0, 0, 0);
        c = __builtin_amdgcn_mfma_f32_16x16x32_bf16(af[mi][0], bg[ni][2], c, 0, 0, 0);
        c = __builtin_amdgcn_mfma_f32_16x16x32_bf16(af[mi][1], bg[ni][0], c, 0, 0, 0);
        c = __builtin_amdgcn_mfma_f32_16x16x32_bf16(af[mi][0], bg[ni][1], c, 0, 0, 0);
        c = __builtin_amdgcn_mfma_f32_16x16x32_bf16(af[mi][0], bg[ni][0], c, 0, 0, 0);
        acc[mi][ni] = c;
      }
    __syncthreads();
  }
#pragma unroll
  for (int mi = 0; mi < 2; ++mi)
#pragma unroll
    for (int ni = 0; ni < 2; ++ni)
#pragma unroll
      for (int r = 0; r < 4; ++r) {
        const int row = m0 + wm + mi * 16 + lg * 4 + r;
        const int col = n0 + wn + ni * 16 + lr;
        float vv = acc[mi][ni][r];
        if (doclip) vv = fminf(fmaxf(vv, -8.0f), 8.0f);
        if (Res) vv += Res[(size_t)row * N + col];
        C[(size_t)row * N + col] = vv;
      }
}

// generic pre-split GEMM (used for Wo): grid (M/64, N/64)
__global__ __launch_bounds__(256) void gemm_ps_kernel(
    const unsigned short* __restrict__ A1, const unsigned short* __restrict__ A2,
    const unsigned short* __restrict__ A3, const unsigned short* __restrict__ B1,
    const unsigned short* __restrict__ B2, const unsigned short* __restrict__ B3,
    float* __restrict__ C, const float* __restrict__ Res,
    int N, int K, int doclip) {
  gemm64_body(A1, A2, A3, B1, B2, B3, C, Res, N, K, doclip,
              blockIdx.x * 64, blockIdx.y * 64);
}

// fused Q/K/V GEMM: blockIdx.y 0..15 -> Wq, 16..19 -> Wk, 20..23 -> Wv
__global__ __launch_bounds__(256) void gemm_qkv_kernel(
    const unsigned short* __restrict__ A1, const unsigned short* __restrict__ A2,
    const unsigned short* __restrict__ A3,
    const unsigned short* __restrict__ Q1, const unsigned short* __restrict__ Q2,
    const unsigned short* __restrict__ Q3,
    const unsigned short* __restrict__ K1, const unsigned short* __restrict__ K2,
    const unsigned short* __restrict__ K3,
    const unsigned short* __restrict__ V1, const unsigned short* __restrict__ V2,
    const unsigned short* __restrict__ V3,
    float* __restrict__ qb, float* __restrict__ kb, float* __restrict__ vb) {
  const int by = blockIdx.y;
  const unsigned short *B1, *B2, *B3;
  float* C;
  int N, n0;
  if (by < 16)      { B1 = Q1; B2 = Q2; B3 = Q3; C = qb; N = 1024; n0 = by * 64; }
  else if (by < 20) { B1 = K1; B2 = K2; B3 = K3; C = kb; N = 256;  n0 = (by - 16) * 64; }
  else              { B1 = V1; B2 = V2; B3 = V3; C = vb; N = 256;  n0 = (by - 20) * 64; }
  gemm64_body(A1, A2, A3, B1, B2, B3, C, nullptr, N, 1024, 1, blockIdx.x * 64, n0);
}

// ---------- prep: fused k-RoPE + split-2 bf16 K (row-major) and V (transposed) ----------
__global__ __launch_bounds__(256) void prep_kv_kernel(
    const float* __restrict__ k, const float* __restrict__ v,
    const float* __restrict__ cosT, const float* __restrict__ sinT,
    unsigned short* __restrict__ Kp1, unsigned short* __restrict__ Kp2,
    unsigned short* __restrict__ Vp1, unsigned short* __restrict__ Vp2) {
  const int key = blockIdx.x;          // 0..1023
  const int kvh = threadIdx.x >> 6;    // 0..3
  const int d = threadIdx.x & 63;
  const int dd = d & 31;
  const float* kbase = &k[((size_t)key * 4 + kvh) * 64];
  const float c = cosT[key * 32 + dd], s = sinT[key * 32 + dd];
  const float u1 = kbase[dd], u2 = kbase[dd + 32];
  const float kk = (d < 32) ? (u1 * c - u2 * s) : (u2 * c + u1 * s);
  const float vv = v[((size_t)key * 4 + kvh) * 64 + d];
  unsigned short a1, a2, b1, b2;
  split2(kk, a1, a2);
  split2(vv, b1, b2);
  const size_t ki = ((size_t)kvh * 1024 + key) * 64 + d;
  Kp1[ki] = a1; Kp2[ki] = a2;
  const size_t vi = ((size_t)kvh * 64 + d) * 1024 + key;
  Vp1[vi] = b1; Vp2[vi] = b2;
}

// ---------- causal GQA flash attention, split-2 bf16 MFMA ----------
// q-RoPE fused into the Q-fragment load; epilogue writes split-3 planes
__global__ __launch_bounds__(256) void attn_kernel(
    const float* __restrict__ q,
    const float* __restrict__ cosT, const float* __restrict__ sinT,
    const unsigned short* __restrict__ Kp1, const unsigned short* __restrict__ Kp2,
    const unsigned short* __restrict__ Vp1, const unsigned short* __restrict__ Vp2,
    unsigned short* __restrict__ o1, unsigned short* __restrict__ o2,
    unsigned short* __restrict__ o3) {
  const int qt = blockIdx.x, h = blockIdx.y, kvh = h >> 2;
  __shared__ unsigned short Ks1[64][72], Ks2[64][72], Vt1[64][72], Vt2[64][72];
  __shared__ unsigned short Ps1[4][16][72], Ps2[4][16][72];
  const int tid = threadIdx.x;
  const int w = tid >> 6, l = tid & 63;
  const int lr = l & 15, lg = l >> 4;

  bfrag aq1[2], aq2[2];
  {
    const int tq = qt * 64 + w * 16 + lr;
    const float* qrow = &q[((size_t)tq * 16 + h) * 64];
    const float4 f00 = *reinterpret_cast<const float4*>(qrow + lg * 8);
    const float4 f01 = *reinterpret_cast<const float4*>(qrow + lg * 8 + 4);
    const float4 f10 = *reinterpret_cast<const float4*>(qrow + 32 + lg * 8);
    const float4 f11 = *reinterpret_cast<const float4*>(qrow + 32 + lg * 8 + 4);
    const float x0[8] = {f00.x, f00.y, f00.z, f00.w, f01.x, f01.y, f01.z, f01.w};
    const float x1[8] = {f10.x, f10.y, f10.z, f10.w, f11.x, f11.y, f11.z, f11.w};
#pragma unroll
    for (int j = 0; j < 8; ++j) {
      const float c = cosT[tq * 32 + lg * 8 + j];
      const float s = sinT[tq * 32 + lg * 8 + j];
      const float r0 = x0[j] * c - x1[j] * s;
      const float r1 = x1[j] * c + x0[j] * s;
      unsigned short p1, p2;
      split2(r0 * 0.125f, p1, p2);
      aq1[0][j] = (short)p1; aq2[0][j] = (short)p2;
      split2(r1 * 0.125f, p1, p2);
      aq1[1][j] = (short)p1; aq2[1][j] = (short)p2;
    }
  }

  f32x4 accO[4] = {{0.f,0.f,0.f,0.f},{0.f,0.f,0.f,0.f},{0.f,0.f,0.f,0.f},{0.f,0.f,0.f,0.f}};
  float mrun[4] = {-INFINITY, -INFINITY, -INFINITY, -INFINITY};
  float lrun[4] = {0.f, 0.f, 0.f, 0.f};

  for (int ti = 0; ti <= qt; ++ti) {
    const int s0 = ti * 64;
    {
      const size_t kbase = ((size_t)kvh * 1024 + s0 + l) * 64 + w * 16;
      *reinterpret_cast<u16x8*>(&Ks1[l][w * 16])     = *reinterpret_cast<const u16x8*>(&Kp1[kbase]);
      *reinterpret_cast<u16x8*>(&Ks1[l][w * 16 + 8]) = *reinterpret_cast<const u16x8*>(&Kp1[kbase + 8]);
      *reinterpret_cast<u16x8*>(&Ks2[l][w * 16])     = *reinterpret_cast<const u16x8*>(&Kp2[kbase]);
      *reinterpret_cast<u16x8*>(&Ks2[l][w * 16 + 8]) = *reinterpret_cast<const u16x8*>(&Kp2[kbase + 8]);
      const size_t vbase = ((size_t)kvh * 64 + l) * 1024 + s0 + w * 16;
      *reinterpret_cast<u16x8*>(&Vt1[l][w * 16])     = *reinterpret_cast<const u16x8*>(&Vp1[vbase]);
      *reinterpret_cast<u16x8*>(&Vt1[l][w * 16 + 8]) = *reinterpret_cast<const u16x8*>(&Vp1[vbase + 8]);
      *reinterpret_cast<u16x8*>(&Vt2[l][w * 16])     = *reinterpret_cast<const u16x8*>(&Vp2[vbase]);
      *reinterpret_cast<u16x8*>(&Vt2[l][w * 16 + 8]) = *reinterpret_cast<const u16x8*>(&Vp2[vbase + 8]);
    }
    __syncthreads();

    f32x4 accS[4] = {{0.f,0.f,0.f,0.f},{0.f,0.f,0.f,0.f},{0.f,0.f,0.f,0.f},{0.f,0.f,0.f,0.f}};
#pragma unroll
    for (int ks = 0; ks < 2; ++ks) {
      const int koff = ks * 32 + lg * 8;
#pragma unroll
      for (int ni = 0; ni < 4; ++ni) {
        const bfrag b1 = *reinterpret_cast<const bfrag*>(&Ks1[ni * 16 + lr][koff]);
        const bfrag b2 = *reinterpret_cast<const bfrag*>(&Ks2[ni * 16 + lr][koff]);
        f32x4 c = accS[ni];
        c = __builtin_amdgcn_mfma_f32_16x16x32_bf16(aq1[ks], b2, c, 0, 0, 0);
        c = __builtin_amdgcn_mfma_f32_16x16x32_bf16(aq2[ks], b1, c, 0, 0, 0);
        c = __builtin_amdgcn_mfma_f32_16x16x32_bf16(aq1[ks], b1, c, 0, 0, 0);
        accS[ni] = c;
      }
    }
    if (ti == qt) {
      const int rowb = w * 16 + lg * 4;
#pragma unroll
      for (int ni = 0; ni < 4; ++ni)
#pragma unroll
        for (int r = 0; r < 4; ++r)
          if (ni * 16 + lr > rowb + r) accS[ni][r] = -INFINITY;
    }
    float alpha[4];
#pragma unroll
    for (int r = 0; r < 4; ++r) {
      float tm = fmaxf(fmaxf(accS[0][r], accS[1][r]), fmaxf(accS[2][r], accS[3][r]));
      tm = fmaxf(tm, __shfl_xor(tm, 1));
      tm = fmaxf(tm, __shfl_xor(tm, 2));
      tm = fmaxf(tm, __shfl_xor(tm, 4));
      tm = fmaxf(tm, __shfl_xor(tm, 8));
      const float mnew = fmaxf(mrun[r], tm);
      alpha[r] = __expf(mrun[r] - mnew);
      mrun[r] = mnew;
      float ps = 0.f;
#pragma unroll
      for (int ni = 0; ni < 4; ++ni) {
        const float pv = __expf(accS[ni][r] - mnew);
        accS[ni][r] = pv;
        ps += pv;
      }
      ps += __shfl_xor(ps, 1);
      ps += __shfl_xor(ps, 2);
      ps += __shfl_xor(ps, 4);
      ps += __shfl_xor(ps, 8);
      lrun[r] = lrun[r] * alpha[r] + ps;
    }
#pragma unroll
    for (int ni = 0; ni < 4; ++ni)
#pragma unroll
      for (int r = 0; r < 4; ++r) {
        const float pv = accS[ni][r];
        unsigned short p1, p2;
        split2(pv, p1, p2);
        Ps1[w][lg * 4 + r][ni * 16 + lr] = p1;
        Ps2[w][lg * 4 + r][ni * 16 + lr] = p2;
      }
#pragma unroll
    for (int ni = 0; ni < 4; ++ni)
#pragma unroll
      for (int r = 0; r < 4; ++r) accO[ni][r] *= alpha[r];

    asm volatile("s_waitcnt lgkmcnt(0)" ::: "memory");

#pragma unroll
    for (int kk = 0; kk < 2; ++kk) {
      const int koff = kk * 32 + lg * 8;
      const bfrag pa1 = *reinterpret_cast<const bfrag*>(&Ps1[w][lr][koff]);
      const bfrag pa2 = *reinterpret_cast<const bfrag*>(&Ps2[w][lr][koff]);
#pragma unroll
      for (int ni = 0; ni < 4; ++ni) {
        const bfrag vb1 = *reinterpret_cast<const bfrag*>(&Vt1[ni * 16 + lr][koff]);
        const bfrag vb2 = *reinterpret_cast<const bfrag*>(&Vt2[ni * 16 + lr][koff]);
        f32x4 c = accO[ni];
        c = __builtin_amdgcn_mfma_f32_16x16x32_bf16(pa1, vb2, c, 0, 0, 0);
        c = __builtin_amdgcn_mfma_f32_16x16x32_bf16(pa2, vb1, c, 0, 0, 0);
        c = __builtin_amdgcn_mfma_f32_16x16x32_bf16(pa1, vb1, c, 0, 0, 0);
        accO[ni] = c;
      }
    }
    __syncthreads();
  }

  const int tqo = qt * 64 + w * 16 + lg * 4;
#pragma unroll
  for (int r = 0; r < 4; ++r) {
    const float inv = 1.0f / lrun[r];
#pragma unroll
    for (int ni = 0; ni < 4; ++ni) {
      const size_t oi = (size_t)(tqo + r) * 1024 + h * 64 + ni * 16 + lr;
      unsigned short s1, s2, s3;
      split3(accO[ni][r] * inv, s1, s2, s3);
      o1[oi] = s1; o2[oi] = s2; o3[oi] = s3;
    }
  }
}

// ---------- router: top-2 of softmax(h2 @ Wr) ----------
__global__ __launch_bounds__(64) void router_kernel(const float* __restrict__ h2,
                                                    const float* __restrict__ Wr,
                                                    int* __restrict__ eidx,
                                                    float* __restrict__ egate) {
  const int t = blockIdx.x;
  const int l = threadIdx.x;
  float p[8];
#pragma unroll
  for (int e = 0; e < 8; ++e) p[e] = 0.f;
  for (int d = l; d < 1024; d += 64) {
    const float x = h2[(size_t)t * 1024 + d];
    const float4 w0 = *reinterpret_cast<const float4*>(&Wr[d * 8]);
    const float4 w1 = *reinterpret_cast<const float4*>(&Wr[d * 8 + 4]);
    p[0] += x * w0.x; p[1] += x * w0.y; p[2] += x * w0.z; p[3] += x * w0.w;
    p[4] += x * w1.x; p[5] += x * w1.y; p[6] += x * w1.z; p[7] += x * w1.w;
  }
#pragma unroll
  for (int off = 32; off; off >>= 1) {
#pragma unroll
    for (int e = 0; e < 8; ++e) p[e] += __shfl_xor(p[e], off);
  }
  if (l == 0) {
    int i0 = 0; float b0 = p[0];
#pragma unroll
    for (int e = 1; e < 8; ++e) if (p[e] > b0) { b0 = p[e]; i0 = e; }
    int i1 = -1; float b1 = -INFINITY;
#pragma unroll
    for (int e = 0; e < 8; ++e) if (e != i0 && p[e] > b1) { b1 = p[e]; i1 = e; }
    const float ex = expf(b1 - b0);
    eidx[t * 2] = i0; eidx[t * 2 + 1] = i1;
    egate[t * 2] = 1.0f / (1.0f + ex);
    egate[t * 2 + 1] = ex / (1.0f + ex);
  }
}

// ---------- dispatch: replicate jnp cumsum slot assignment ----------
__global__ __launch_bounds__(256) void dispatch_kernel(
    const int* __restrict__ eidx, int* __restrict__ cnt,
    int* __restrict__ slot_token, int* __restrict__ entry_slot) {
  __shared__ unsigned char ef[2048];
  __shared__ unsigned short ch[256][8];
  const int tid = threadIdx.x;
  for (int i = tid; i < 2048; i += 256) ef[i] = (unsigned char)eidx[i];
  __syncthreads();
  int loc[8];
#pragma unroll
  for (int e = 0; e < 8; ++e) loc[e] = 0;
  const int base = tid * 8;
  for (int j = 0; j < 8; ++j) {
    const int ee = ef[base + j];
#pragma unroll
    for (int e = 0; e < 8; ++e) loc[e] += (ee == e);
  }
#pragma unroll
  for (int e = 0; e < 8; ++e) ch[tid][e] = (unsigned short)loc[e];
  __syncthreads();
  int pre[8];
#pragma unroll
  for (int e = 0; e < 8; ++e) pre[e] = 0;
  for (int t2 = 0; t2 < tid; ++t2) {
#pragma unroll
    for (int e = 0; e < 8; ++e) pre[e] += ch[t2][e];
  }
  if (tid == 255) {
#pragma unroll
    for (int e = 0; e < 8; ++e) cnt[e] = min(pre[e] + loc[e], 512);
  }
  for (int j = 0; j < 8; ++j) {
    const int i = base + j;
    const int ee = ef[i];
    int slot = 0;
#pragma unroll
    for (int e = 0; e < 8; ++e) {
      if (e == ee) { slot = pre[e]; pre[e] = pre[e] + 1; }
    }
    if (slot < 512) {
      slot_token[ee * 512 + slot] = i >> 1;
      entry_slot[i] = slot;
    } else {
      entry_slot[i] = -1;
    }
  }
}

// ---------- pre-convert dispatched tokens to bf16: xbf[e][slot][1024] ----------
__global__ __launch_bounds__(256) void moe_xbf_kernel(
    const float* __restrict__ h2, const int* __restrict__ cnt,
    const int* __restrict__ slot_token, unsigned short* __restrict__ xbf) {
  const int row = blockIdx.x;          // e*512 + slot
  const int e = row >> 9, slot = row & 511;
  const int tid = threadIdx.x;
  ushort4 o;
  if (slot < cnt[e]) {
    const int tok = slot_token[row];
    const float4 f = *reinterpret_cast<const float4*>(&h2[(size_t)tok * 1024 + tid * 4]);
    o = make_ushort4(bf16_rne(f.x), bf16_rne(f.y), bf16_rne(f.z), bf16_rne(f.w));
  } else {
    o = make_ushort4(0, 0, 0, 0);
  }
  *reinterpret_cast<ushort4*>(&xbf[(size_t)row * 1024 + tid * 4]) = o;
}

// ---------- MoE pass 1 (round-5 exact): act = silu(X@Wg)*(X@Wu) ----------
// grid 512 flat: e = bx&7 (expert->XCD), nt = bx>>3 (BN=32). BM=512 (whole expert).
__global__ __launch_bounds__(256, 2) void moe_mlp1_kernel(
    const unsigned short* __restrict__ xbf, const float* __restrict__ Wg,
    const float* __restrict__ Wu, const int* __restrict__ cnt,
    unsigned short* __restrict__ act) {
  const int bx = blockIdx.x;
  const int e = bx & 7, nt = bx >> 3;
  const int n0 = nt * 32;
  const int ce = cnt[e];
  if (ce <= 0) return;
  __shared__ alignas(16) unsigned short BgL[2][32][72], BuL[2][32][72];
  const int tid = threadIdx.x;
  const int w = tid >> 6, l = tid & 63;
  const int lr = l & 15, lg = l >> 4;
  const int wc = tid & 31, kq8 = tid >> 5;
  const float* WgE = Wg + (size_t)e * 1024 * 2048 + (size_t)kq8 * 8 * 2048 + n0 + wc;
  const float* WuE = Wu + (size_t)e * 1024 * 2048 + (size_t)kq8 * 8 * 2048 + n0 + wc;
  const unsigned short* xbE = xbf + (size_t)e * 512 * 1024;

  f32x4 accG[8][2], accU[8][2];
#pragma unroll
  for (int mi = 0; mi < 8; ++mi)
#pragma unroll
    for (int ni = 0; ni < 2; ++ni) {
      accG[mi][ni] = (f32x4){0.f, 0.f, 0.f, 0.f};
      accU[mi][ni] = (f32x4){0.f, 0.f, 0.f, 0.f};
    }

  float wgr[8], wur[8];
#pragma unroll
  for (int j = 0; j < 8; ++j) { wgr[j] = WgE[(size_t)j * 2048]; wur[j] = WuE[(size_t)j * 2048]; }
  {
    u16x8 g8, u8;
#pragma unroll
    for (int j = 0; j < 8; ++j) { g8[j] = bf16_rne(wgr[j]); u8[j] = bf16_rne(wur[j]); }
    *reinterpret_cast<u16x8*>(&BgL[0][wc][kq8 * 8]) = g8;
    *reinterpret_cast<u16x8*>(&BuL[0][wc][kq8 * 8]) = u8;
  }
#pragma unroll
  for (int j = 0; j < 8; ++j) { wgr[j] = WgE[(size_t)(64 + j) * 2048]; wur[j] = WuE[(size_t)(64 + j) * 2048]; }
  __syncthreads();

  for (int t = 0; t < 16; ++t) {
    const int cur = t & 1;
    bfrag bgf[2][2], buf2[2][2];
#pragma unroll
    for (int ni = 0; ni < 2; ++ni)
#pragma unroll
      for (int kf = 0; kf < 2; ++kf) {
        bgf[ni][kf]  = *reinterpret_cast<const bfrag*>(&BgL[cur][ni * 16 + lr][kf * 32 + lg * 8]);
        buf2[ni][kf] = *reinterpret_cast<const bfrag*>(&BuL[cur][ni * 16 + lr][kf * 32 + lg * 8]);
      }
    u16x8 g8, u8;
    if (t < 15) {
#pragma unroll
      for (int j = 0; j < 8; ++j) { g8[j] = bf16_rne(wgr[j]); u8[j] = bf16_rne(wur[j]); }
    }
    if (t < 14) {
      const size_t kb = (size_t)(t + 2) * 64;
#pragma unroll
      for (int j = 0; j < 8; ++j) { wgr[j] = WgE[(kb + j) * 2048]; wur[j] = WuE[(kb + j) * 2048]; }
    }
    const int kA = t * 64 + lg * 8;
#pragma unroll
    for (int mi = 0; mi < 8; ++mi) {
      const int row0 = (mi * 4 + w) * 16;   // wave-interleaved 16-row groups
      if (row0 < ce) {
        const unsigned short* ap = &xbE[(size_t)(row0 + lr) * 1024 + kA];
        const bfrag a0 = *reinterpret_cast<const bfrag*>(ap);
        const bfrag a1 = *reinterpret_cast<const bfrag*>(ap + 32);
#pragma unroll
        for (int ni = 0; ni < 2; ++ni) {
          accG[mi][ni] = __builtin_amdgcn_mfma_f32_16x16x32_bf16(a0, bgf[ni][0], accG[mi][ni], 0, 0, 0);
          accG[mi][ni] = __builtin_amdgcn_mfma_f32_16x16x32_bf16(a1, bgf[ni][1], accG[mi][ni], 0, 0, 0);
          accU[mi][ni] = __builtin_amdgcn_mfma_f32_16x16x32_bf16(a0, buf2[ni][0], accU[mi][ni], 0, 0, 0);
          accU[mi][ni] = __builtin_amdgcn_mfma_f32_16x16x32_bf16(a1, buf2[ni][1], accU[mi][ni], 0, 0, 0);
        }
      }
    }
    if (t < 15) {
      *reinterpret_cast<u16x8*>(&BgL[cur ^ 1][wc][kq8 * 8]) = g8;
      *reinterpret_cast<u16x8*>(&BuL[cur ^ 1][wc][kq8 * 8]) = u8;
    }
    __syncthreads();
  }
#pragma unroll
  for (int mi = 0; mi < 8; ++mi) {
    const int row0 = (mi * 4 + w) * 16;
    if (row0 < ce) {
#pragma unroll
      for (int r = 0; r < 4; ++r) {
        const int m = row0 + lg * 4 + r;
        if (m < ce) {
#pragma unroll
          for (int ni = 0; ni < 2; ++ni) {
            const float gg = accG[mi][ni][r];
            const float uu = accU[mi][ni][r];
            const float a = gg / (1.0f + __expf(-gg)) * uu;
            act[((size_t)e * 512 + m) * 2048 + n0 + ni * 16 + lr] = bf16_rne(a);
          }
        }
      }
    }
  }
}

// ---------- MoE pass 2 (round-5 exact, split-K=2): ob_part = act @ Wd ----------
// grid 512 flat: e = bx&7, nt = (bx>>3)&31, kc = bx>>8. BM=512, BN=32, K-slice 1024.
__global__ __launch_bounds__(256, 2) void moe_mlp2_kernel(
    const unsigned short* __restrict__ act, const float* __restrict__ Wd,
    const int* __restrict__ cnt, float* __restrict__ ob) {
  const int bx = blockIdx.x;
  const int e = bx & 7;
  const int rr = bx >> 3;
  const int nt = rr & 31, kc = rr >> 5;
  const int n0 = nt * 32;
  const int ce = cnt[e];
  if (ce <= 0) return;
  __shared__ alignas(16) unsigned short BsL[2][32][72];
  const int tid = threadIdx.x;
  const int w = tid >> 6, l = tid & 63;
  const int lr = l & 15, lg = l >> 4;
  const int wc = tid & 31, kq8 = tid >> 5;
  const unsigned short* actE = act + (size_t)e * 512 * 2048 + (size_t)kc * 1024;
  const float* WdE = Wd + (size_t)e * 2048 * 1024 + (size_t)(kc * 1024 + kq8 * 8) * 1024 + n0 + wc;
  float* obE = ob + (size_t)kc * 8 * 512 * 1024;

  f32x4 acc[8][2];
#pragma unroll
  for (int mi = 0; mi < 8; ++mi)
#pragma unroll
    for (int ni = 0; ni < 2; ++ni) acc[mi][ni] = (f32x4){0.f, 0.f, 0.f, 0.f};

  float wdr[8];
#pragma unroll
  for (int j = 0; j < 8; ++j) wdr[j] = WdE[(size_t)j * 1024];
  {
    u16x8 d8;
#pragma unroll
    for (int j = 0; j < 8; ++j) d8[j] = bf16_rne(wdr[j]);
    *reinterpret_cast<u16x8*>(&BsL[0][wc][kq8 * 8]) = d8;
  }
#pragma unroll
  for (int j = 0; j < 8; ++j) wdr[j] = WdE[(size_t)(64 + j) * 1024];
  __syncthreads();

  for (int t = 0; t < 16; ++t) {
    const int cur = t & 1;
    bfrag bf2[2][2];
#pragma unroll
    for (int ni = 0; ni < 2; ++ni)
#pragma unroll
      for (int kf = 0; kf < 2; ++kf)
        bf2[ni][kf] = *reinterpret_cast<const bfrag*>(&BsL[cur][ni * 16 + lr][kf * 32 + lg * 8]);
    u16x8 d8;
    if (t < 15) {
#pragma unroll
      for (int j = 0; j < 8; ++j) d8[j] = bf16_rne(wdr[j]);
    }
    if (t < 14) {
      const size_t kb = (size_t)(t + 2) * 64;
#pragma unroll
      for (int j = 0; j < 8; ++j) wdr[j] = WdE[(kb + j) * 1024];
    }
    const int kA = t * 64 + lg * 8;
#pragma unroll
    for (int mi = 0; mi < 8; ++mi) {
      const int row0 = (mi * 4 + w) * 16;
      if (row0 < ce) {
        const unsigned short* ap = &actE[(size_t)(row0 + lr) * 2048 + kA];
        const bfrag a0 = *reinterpret_cast<const bfrag*>(ap);
        const bfrag a1 = *reinterpret_cast<const bfrag*>(ap + 32);
#pragma unroll
        for (int ni = 0; ni < 2; ++ni) {
          acc[mi][ni] = __builtin_amdgcn_mfma_f32_16x16x32_bf16(a0, bf2[ni][0], acc[mi][ni], 0, 0, 0);
          acc[mi][ni] = __builtin_amdgcn_mfma_f32_16x16x32_bf16(a1, bf2[ni][1], acc[mi][ni], 0, 0, 0);
        }
      }
    }
    if (t < 15) {
      *reinterpret_cast<u16x8*>(&BsL[cur ^ 1][wc][kq8 * 8]) = d8;
    }
    __syncthreads();
  }
#pragma unroll
  for (int mi = 0; mi < 8; ++mi) {
    const int row0 = (mi * 4 + w) * 16;
    if (row0 < ce) {
#pragma unroll
      for (int r = 0; r < 4; ++r) {
        const int m = row0 + lg * 4 + r;
        if (m < ce) {
#pragma unroll
          for (int ni = 0; ni < 2; ++ni)
            obE[((size_t)e * 512 + m) * 1024 + n0 + ni * 16 + lr] = acc[mi][ni][r];
        }
      }
    }
  }
}

// ---------- combine: out += sum_k gate * (ob0+ob1)[e_k][slot_k] ----------
__global__ __launch_bounds__(256) void combine_kernel(
    const float* __restrict__ ob, const int* __restrict__ eidx,
    const float* __restrict__ egate, const int* __restrict__ entry_slot,
    float* __restrict__ out) {
  const int t = blockIdx.x;
  const int d = threadIdx.x * 4;
  const size_t half = (size_t)8 * 512 * 1024;
  float4 o4 = *reinterpret_cast<float4*>(&out[(size_t)t * 1024 + d]);
#pragma unroll
  for (int kk = 0; kk < 2; ++kk) {
    const int i = t * 2 + kk;
    const int s = entry_slot[i];
    if (s >= 0) {
      const int e = eidx[i];
      const float g = egate[i];
      const size_t base = ((size_t)e * 512 + s) * 1024 + d;
      const float4 c0 = *reinterpret_cast<const float4*>(&ob[base]);
      const float4 c1 = *reinterpret_cast<const float4*>(&ob[half + base]);
      o4.x += g * (c0.x + c1.x); o4.y += g * (c0.y + c1.y);
      o4.z += g * (c0.z + c1.z); o4.w += g * (c0.w + c1.w);
    }
  }
  *reinterpret_cast<float4*>(&out[(size_t)t * 1024 + d]) = o4;
}

extern "C" void kernel_launch(void* const* d_in, const int* in_sizes, int n_in,
                              void* d_out, int out_size, void* d_ws, size_t ws_size,
                              hipStream_t stream) {
  const float* hidden = (const float*)d_in[0];
  const int* posids  = (const int*)d_in[1];
  const float* ln1w  = (const float*)d_in[2];
  const float* ln2w  = (const float*)d_in[3];
  const float* Wq    = (const float*)d_in[4];
  const float* Wk    = (const float*)d_in[5];
  const float* Wv    = (const float*)d_in[6];
  const float* Wo    = (const float*)d_in[7];
  const float* Wr    = (const float*)d_in[8];
  const float* Wg    = (const float*)d_in[9];
  const float* Wu    = (const float*)d_in[10];
  const float* Wd    = (const float*)d_in[11];
  float* out = (float*)d_out;

  char* p = (char*)d_ws;
  auto alloc = [&](size_t bytes) { char* r = p; p += (bytes + 255) & ~(size_t)255; return r; };
  float* qb   = (float*)alloc((size_t)1024 * 1024 * 4);
  float* kb   = (float*)alloc((size_t)1024 * 256 * 4);
  float* vb   = (float*)alloc((size_t)1024 * 256 * 4);
  float* h2   = (float*)alloc((size_t)1024 * 1024 * 4);
  unsigned short* act = (unsigned short*)alloc((size_t)8 * 512 * 2048 * 2);
  float* obuf = (float*)alloc((size_t)2 * 8 * 512 * 1024 * 4);
  int* eidx   = (int*)alloc(2048 * 4);
  float* egate = (float*)alloc(2048 * 4);
  int* cnt    = (int*)alloc(8 * 4);
  int* slot_token = (int*)alloc((size_t)8 * 512 * 4);
  int* entry_slot = (int*)alloc(2048 * 4);
  float* cosT = (float*)alloc((size_t)1024 * 32 * 4);
  float* sinT = (float*)alloc((size_t)1024 * 32 * 4);
  unsigned short* Kp1 = (unsigned short*)alloc((size_t)4 * 1024 * 64 * 2);
  unsigned short* Kp2 = (unsigned short*)alloc((size_t)4 * 1024 * 64 * 2);
  unsigned short* Vp1 = (unsigned short*)alloc((size_t)4 * 1024 * 64 * 2);
  unsigned short* Vp2 = (unsigned short*)alloc((size_t)4 * 1024 * 64 * 2);
  unsigned short* xbf = (unsigned short*)alloc((size_t)8 * 512 * 1024 * 2);
  // split-3 planes
  const size_t MK = (size_t)1024 * 1024;
  unsigned short* h1s[3], *aos[3], *wqt[3], *wkt[3], *wvt[3], *wot[3];
  for (int s = 0; s < 3; ++s) h1s[s] = (unsigned short*)alloc(MK * 2);
  for (int s = 0; s < 3; ++s) aos[s] = (unsigned short*)alloc(MK * 2);
  for (int s = 0; s < 3; ++s) wqt[s] = (unsigned short*)alloc(MK * 2);
  for (int s = 0; s < 3; ++s) wkt[s] = (unsigned short*)alloc((size_t)256 * 1024 * 2);
  for (int s = 0; s < 3; ++s) wvt[s] = (unsigned short*)alloc((size_t)256 * 1024 * 2);
  for (int s = 0; s < 3; ++s) wot[s] = (unsigned short*)alloc(MK * 2);

  split3t_all_kernel<<<2688, 256, 0, stream>>>(Wq, Wk, Wv, Wo, posids, cosT, sinT,
      wqt[0], wqt[1], wqt[2], wkt[0], wkt[1], wkt[2],
      wvt[0], wvt[1], wvt[2], wot[0], wot[1], wot[2]);

  ln_split3_kernel<<<1024, 256, 0, stream>>>(hidden, ln1w, h1s[0], h1s[1], h1s[2]);
  gemm_qkv_kernel<<<dim3(16, 24), 256, 0, stream>>>(h1s[0], h1s[1], h1s[2],
      wqt[0], wqt[1], wqt[2], wkt[0], wkt[1], wkt[2], wvt[0], wvt[1], wvt[2],
      qb, kb, vb);
  prep_kv_kernel<<<1024, 256, 0, stream>>>(kb, vb, cosT, sinT, Kp1, Kp2, Vp1, Vp2);
  attn_kernel<<<dim3(16, 16), 256, 0, stream>>>(qb, cosT, sinT, Kp1, Kp2, Vp1, Vp2,
      aos[0], aos[1], aos[2]);
  gemm_ps_kernel<<<dim3(16, 16), 256, 0, stream>>>(aos[0], aos[1], aos[2],
      wot[0], wot[1], wot[2], out, hidden, 1024, 1024, 0);
  ln_kernel<<<1024, 256, 0, stream>>>(out, ln2w, h2);
  router_kernel<<<1024, 64, 0, stream>>>(h2, Wr, eidx, egate);
  dispatch_kernel<<<1, 256, 0, stream>>>(eidx, cnt, slot_token, entry_slot);
  moe_xbf_kernel<<<4096, 256, 0, stream>>>(h2, cnt, slot_token, xbf);
  moe_mlp1_kernel<<<512, 256, 0, stream>>>(xbf, Wg, Wu, cnt, act);
  moe_mlp2_kernel<<<512, 256, 0, stream>>>(act, Wd, cnt, obuf);
  combine_kernel<<<1024, 256, 0, stream>>>(obuf, eidx, egate, entry_slot, out);
}